// Round 5
// baseline (1890.763 us; speedup 1.0000x reference)
//
#include <hip/hip_runtime.h>

#define NB 64
#define NO 100
#define NI 2048
#define ND 16
#define NK 8

// ws layout (float offsets)
#define WS_H    0            // h: 64*256*24*24 = 9437184
#define WS_U    9437184      // u: 64*2048*8 = 1048576
#define WS_BB   10485760     // b logits: 64*100*2048 = 13107200  (pp overlaps here pre-routing)
#define WS_CB   23592960     // c: 13107200                        (wT overlaps here pre-routing)
#define WS_SP   36700160     // s partials: 100*16*64*16 = 1638400
#define WS_V    38338560     // v: 64*100*16 = 102400
// total 38440960 floats = 153.8 MB
#define WS_PP   WS_BB        // conv2 partials: 8*64*256*64 = 8388608
#define WS_WT   WS_CB        // wT: 256*81*256 = 5308416

// ---------------- conv1: [64,3,32,32] -> relu -> [64,256,24,24] ----------------
__global__ __launch_bounds__(256) void conv1_kernel(const float* __restrict__ x,
        const float* __restrict__ w, const float* __restrict__ bias,
        float* __restrict__ h) {
    const int b = blockIdx.x;
    const int ocg = blockIdx.y;          // 16 oc per block
    __shared__ float xl[3 * 32 * 32];
    __shared__ float wl[16 * 243];
    const int tid = threadIdx.x;
    for (int idx = tid; idx < 3072; idx += 256) xl[idx] = x[b * 3072 + idx];
    for (int idx = tid; idx < 16 * 243; idx += 256)
        wl[idx] = w[ocg * 16 * 243 + idx];
    __syncthreads();
    const int lane = tid & 63;
    const int wg = tid >> 6;             // 0..3 -> 4 oc each
    float acc[4][9];
    #pragma unroll
    for (int jj = 0; jj < 4; ++jj) {
        float bv = bias[ocg * 16 + wg * 4 + jj];
        #pragma unroll
        for (int j = 0; j < 9; ++j) acc[jj][j] = bv;
    }
    int xbase[9];
    #pragma unroll
    for (int j = 0; j < 9; ++j) {
        int p = lane + 64 * j;           // 576 positions exactly
        xbase[j] = (p / 24) * 32 + (p % 24);
    }
    for (int ic = 0; ic < 3; ++ic)
        for (int ky = 0; ky < 9; ++ky) {
            #pragma unroll
            for (int kx = 0; kx < 9; ++kx) {
                float wv[4];
                #pragma unroll
                for (int jj = 0; jj < 4; ++jj)
                    wv[jj] = wl[(wg * 4 + jj) * 243 + ic * 81 + ky * 9 + kx];
                #pragma unroll
                for (int j = 0; j < 9; ++j) {
                    float xv = xl[ic * 1024 + xbase[j] + ky * 32 + kx];
                    #pragma unroll
                    for (int jj = 0; jj < 4; ++jj)
                        acc[jj][j] = fmaf(xv, wv[jj], acc[jj][j]);
                }
            }
        }
    #pragma unroll
    for (int jj = 0; jj < 4; ++jj) {
        int oc = ocg * 16 + wg * 4 + jj;
        #pragma unroll
        for (int j = 0; j < 9; ++j) {
            int p = lane + 64 * j;
            h[(b * 256 + oc) * 576 + p] = fmaxf(acc[jj][j], 0.f);
        }
    }
}

// ---------------- transpose pcap_w -> wT[ic][kk][oc] ----------------
__global__ __launch_bounds__(256) void transpose_w_kernel(const float* __restrict__ w,
        float* __restrict__ wT) {
    const int ic = blockIdx.x;           // 0..255
    const int ocq = blockIdx.y;          // 0..3 (64 oc each)
    __shared__ float tl[64][85];         // pad 85: gcd(21,32)=1, conflict-free
    const int tid = threadIdx.x;
    for (int f = tid; f < 5184; f += 256) {
        int oc = f / 81, kk = f % 81;
        tl[oc][kk] = w[(size_t)(ocq * 64 + oc) * 20736 + ic * 81 + kk];
    }
    __syncthreads();
    for (int f = tid; f < 5184; f += 256) {
        int kk = f >> 6, oc = f & 63;
        wT[((size_t)ic * 81 + kk) * 256 + ocq * 64 + oc] = tl[oc][kk];
    }
}

// ---------------- conv2 partial: K-split implicit GEMM ----------------
// block: 64 oc x 128 pos (2 batches) x 32-ic slice. thread: 8 oc x 4 pos.
// Epilogue MUST be float4 stores: scalar stores at 16B lane-stride caused
// 28x write amplification (937MB for a 33.5MB buffer, round 4 counters).
__global__ __launch_bounds__(256, 4) void conv2_partial_kernel(
        const float* __restrict__ h, const float* __restrict__ wT,
        float* __restrict__ pp) {
    const int bpair = blockIdx.x;        // 0..31
    const int ocb = blockIdx.y;          // 0..3  (64 oc)
    const int ks = blockIdx.z;           // 0..7  (32 ic)
    __shared__ __align__(16) float wl[81 * 64];   // [kk][oc] linear
    __shared__ __align__(16) float xl[2 * 576];   // [bhalf][24*24]
    const int tid = threadIdx.x;
    const int ocg = tid & 7;             // 8 oc groups of 8
    const int posg = tid >> 3;           // 0..31
    const int bh = posg >> 4;            // batch half
    const int sub = posg & 15;           // pos chunk: pos = 4*sub + p
    const int oy = sub >> 1;             // output row 0..7
    const int ox0 = (sub & 1) * 4;       // output col base 0 or 4
    float acc[8][4];
    #pragma unroll
    for (int j = 0; j < 8; ++j)
        #pragma unroll
        for (int p = 0; p < 4; ++p) acc[j][p] = 0.f;
    const int ic0 = ks * 32;
    #pragma unroll 1
    for (int ic = ic0; ic < ic0 + 32; ++ic) {
        __syncthreads();
        // stage weights: 81 rows x 64 oc = 1296 float4, coalesced, LDS-linear
        const float4* wsrc = (const float4*)(wT + ((size_t)ic * 81) * 256 + ocb * 64);
        for (int it = tid; it < 1296; it += 256)
            ((float4*)wl)[it] = wsrc[(it >> 4) * 64 + (it & 15)];
        // stage x: 2 batches x 576 = 288 float4
        for (int it = tid; it < 288; it += 256) {
            int b2 = (it >= 144);
            int idx = it - b2 * 144;
            ((float4*)xl)[it] =
                ((const float4*)(h + ((size_t)(bpair * 2 + b2) * 256 + ic) * 576))[idx];
        }
        __syncthreads();
        const float* xb = xl + bh * 576;
        #pragma unroll
        for (int ky = 0; ky < 9; ++ky) {
            const float* xrow = xb + (2 * oy + ky) * 24 + 2 * ox0;
            #pragma unroll
            for (int kx = 0; kx < 9; ++kx) {
                const int kk = ky * 9 + kx;
                const float4 wa = *(const float4*)&wl[kk * 64 + ocg * 8];
                const float4 wb = *(const float4*)&wl[kk * 64 + ocg * 8 + 4];
                float xv[4];
                #pragma unroll
                for (int p = 0; p < 4; ++p) xv[p] = xrow[2 * p + kx];
                #pragma unroll
                for (int p = 0; p < 4; ++p) {
                    acc[0][p] = fmaf(wa.x, xv[p], acc[0][p]);
                    acc[1][p] = fmaf(wa.y, xv[p], acc[1][p]);
                    acc[2][p] = fmaf(wa.z, xv[p], acc[2][p]);
                    acc[3][p] = fmaf(wa.w, xv[p], acc[3][p]);
                    acc[4][p] = fmaf(wb.x, xv[p], acc[4][p]);
                    acc[5][p] = fmaf(wb.y, xv[p], acc[5][p]);
                    acc[6][p] = fmaf(wb.z, xv[p], acc[6][p]);
                    acc[7][p] = fmaf(wb.w, xv[p], acc[7][p]);
                }
            }
        }
    }
    const int b = bpair * 2 + bh;
    #pragma unroll
    for (int j = 0; j < 8; ++j) {
        const int oc = ocb * 64 + ocg * 8 + j;
        float4 st;
        st.x = acc[j][0]; st.y = acc[j][1]; st.z = acc[j][2]; st.w = acc[j][3];
        // pos = 4*sub + p, p contiguous -> one dwordx4 per j (16B aligned)
        *(float4*)&pp[(((size_t)ks * 64 + b) * 256 + oc) * 64 + 4 * sub] = st;
    }
}

// -------- reduce partials over ks, +bias, squash capsule rows of 8 -> u --------
__global__ __launch_bounds__(256) void reduce_bias_squash_kernel(
        const float* __restrict__ pp, const float* __restrict__ bias,
        float* __restrict__ u) {
    const int cap = blockIdx.x * 256 + threadIdx.x;   // 131072 capsules
    const int b = cap >> 11;
    const int rem = cap & 2047;
    const int oc = rem >> 3;
    const int oy = rem & 7;
    float4 sa = {0.f, 0.f, 0.f, 0.f}, sb = {0.f, 0.f, 0.f, 0.f};
    #pragma unroll
    for (int ks = 0; ks < 8; ++ks) {
        const float4* p4 = (const float4*)&pp[(((size_t)ks * 64 + b) * 256 + oc) * 64 + oy * 8];
        float4 a = p4[0], c = p4[1];
        sa.x += a.x; sa.y += a.y; sa.z += a.z; sa.w += a.w;
        sb.x += c.x; sb.y += c.y; sb.z += c.z; sb.w += c.w;
    }
    const float bv = bias[oc];
    sa.x += bv; sa.y += bv; sa.z += bv; sa.w += bv;
    sb.x += bv; sb.y += bv; sb.z += bv; sb.w += bv;
    float s2 = sa.x * sa.x + sa.y * sa.y + sa.z * sa.z + sa.w * sa.w
             + sb.x * sb.x + sb.y * sb.y + sb.z * sb.z + sb.w * sb.w;
    float scale = (s2 / (1.f + s2)) / sqrtf(s2 + 1e-8f);
    sa.x *= scale; sa.y *= scale; sa.z *= scale; sa.w *= scale;
    sb.x *= scale; sb.y *= scale; sb.z *= scale; sb.w *= scale;
    float4* up = (float4*)&u[(size_t)cap * 8];
    up[0] = sa;
    up[1] = sb;
}

// -------- weighted sum: s_part[o][st][b][d] = sum_i c[b,o,i]*u_hat[b,o,i,d] --------
template <int UNIFORM>
__global__ __launch_bounds__(256) void r_weighted_kernel(
        const float* __restrict__ W, const float* __restrict__ u,
        const float* __restrict__ cbuf, float* __restrict__ sp) {
    const int o = blockIdx.x;
    const int st = blockIdx.y;                 // 16 supertiles of 128 i
    __shared__ __align__(16) float Wl[16 * 128];   // [ii][d][k]
    __shared__ __align__(16) float ul[64 * 128];   // [b][ii][k]
    __shared__ float cl[64 * 16];                  // [b][ii]
    const int tid = threadIdx.x;
    const int d = tid & 15;
    const int bg = tid >> 4;
    float acc[4] = {0.f, 0.f, 0.f, 0.f};
    for (int sub = 0; sub < 8; ++sub) {
        const int i0 = st * 128 + sub * 16;
        __syncthreads();
        for (int idx = tid; idx < 2048; idx += 256)
            Wl[idx] = W[o * 262144 + i0 * 128 + idx];
        for (int idx = tid; idx < 8192; idx += 256) {
            int bb = idx >> 7, r = idx & 127;
            ul[idx] = u[bb * 16384 + i0 * 8 + r];
        }
        if (!UNIFORM) {
            for (int idx = tid; idx < 1024; idx += 256) {
                int bb = idx >> 4, ii = idx & 15;
                cl[idx] = cbuf[bb * (NO * NI) + o * NI + i0 + ii];
            }
        }
        __syncthreads();
        for (int ii = 0; ii < 16; ++ii) {
            const float4 wa = *(const float4*)&Wl[ii * 128 + d * 8];
            const float4 wb = *(const float4*)&Wl[ii * 128 + d * 8 + 4];
            #pragma unroll
            for (int j = 0; j < 4; ++j) {
                const int bb = bg + 16 * j;
                const float4 ua = *(const float4*)&ul[bb * 128 + ii * 8];
                const float4 ub = *(const float4*)&ul[bb * 128 + ii * 8 + 4];
                float uh = wa.x * ua.x + wa.y * ua.y + wa.z * ua.z + wa.w * ua.w
                         + wb.x * ub.x + wb.y * ub.y + wb.z * ub.z + wb.w * ub.w;
                float cv = UNIFORM ? 0.01f : cl[bb * 16 + ii];
                acc[j] = fmaf(cv, uh, acc[j]);
            }
        }
    }
    #pragma unroll
    for (int j = 0; j < 4; ++j) {
        const int bb = bg + 16 * j;
        sp[((o * 16 + st) * 64 + bb) * 16 + d] = acc[j];
    }
}

// -------- reduce partials over st, squash over d, write v (or final out) --------
__global__ __launch_bounds__(256) void squash_v_kernel(const float* __restrict__ sp,
        float* __restrict__ dest) {
    const int t = blockIdx.x * 256 + threadIdx.x;  // 102400 slots
    const int d = t & 15;
    const int cap = t >> 4;                        // o*64 + b
    const int o = cap >> 6;
    const int bb = cap & 63;
    float s = 0.f;
    #pragma unroll
    for (int st = 0; st < 16; ++st)
        s += sp[((o * 16 + st) * 64 + bb) * 16 + d];
    float s2 = s * s;
    #pragma unroll
    for (int off = 1; off < 16; off <<= 1)
        s2 += __shfl_xor(s2, off, 16);
    float scale = (s2 / (1.f + s2)) / sqrtf(s2 + 1e-8f);
    dest[(bb * NO + o) * ND + d] = s * scale;
}

// -------- logits: b[b,o,i] (+)= sum_d u_hat[b,o,i,d] * v[b,o,d] --------
template <int ADD>
__global__ __launch_bounds__(256) void r_logits_kernel(
        const float* __restrict__ W, const float* __restrict__ u,
        const float* __restrict__ v, float* __restrict__ bbuf) {
    const int o = blockIdx.x;
    const int st = blockIdx.y;
    __shared__ __align__(16) float Wl[16 * 128];
    __shared__ __align__(16) float ul[64 * 128];
    __shared__ float vl[64 * 16];
    const int tid = threadIdx.x;
    const int ii = tid & 15;
    const int bg = tid >> 4;
    for (int idx = tid; idx < 1024; idx += 256) {
        int bb = idx >> 4, dd = idx & 15;
        vl[idx] = v[(bb * NO + o) * ND + dd];
    }
    for (int sub = 0; sub < 8; ++sub) {
        const int i0 = st * 128 + sub * 16;
        __syncthreads();
        for (int idx = tid; idx < 2048; idx += 256)
            Wl[idx] = W[o * 262144 + i0 * 128 + idx];
        for (int idx = tid; idx < 8192; idx += 256) {
            int bb = idx >> 7, r = idx & 127;
            ul[idx] = u[bb * 16384 + i0 * 8 + r];
        }
        __syncthreads();
        float4 ua[4], ub[4];
        #pragma unroll
        for (int j = 0; j < 4; ++j) {
            const int bb = bg + 16 * j;
            ua[j] = *(const float4*)&ul[bb * 128 + ii * 8];
            ub[j] = *(const float4*)&ul[bb * 128 + ii * 8 + 4];
        }
        float tmp[4] = {0.f, 0.f, 0.f, 0.f};
        for (int dd = 0; dd < 16; ++dd) {
            const float4 wa = *(const float4*)&Wl[ii * 128 + dd * 8];
            const float4 wb = *(const float4*)&Wl[ii * 128 + dd * 8 + 4];
            #pragma unroll
            for (int j = 0; j < 4; ++j) {
                float uh = wa.x * ua[j].x + wa.y * ua[j].y + wa.z * ua[j].z + wa.w * ua[j].w
                         + wb.x * ub[j].x + wb.y * ub[j].y + wb.z * ub[j].z + wb.w * ub[j].w;
                tmp[j] = fmaf(uh, vl[(bg + 16 * j) * 16 + dd], tmp[j]);
            }
        }
        #pragma unroll
        for (int j = 0; j < 4; ++j) {
            const int bb = bg + 16 * j;
            const int addr = bb * (NO * NI) + o * NI + i0 + ii;
            bbuf[addr] = (ADD ? bbuf[addr] : 0.f) + tmp[j];
        }
    }
}

// -------- softmax over o (axis=1) of b -> c --------
__global__ __launch_bounds__(256) void softmax_kernel(const float* __restrict__ bbuf,
        float* __restrict__ cbuf) {
    const int bb = blockIdx.x >> 3;
    const int i = (blockIdx.x & 7) * 256 + threadIdx.x;
    const float* col = bbuf + bb * (NO * NI) + i;
    float m = -1e30f;
    for (int o = 0; o < NO; ++o) m = fmaxf(m, col[o * NI]);
    float s = 0.f;
    for (int o = 0; o < NO; ++o) s += __expf(col[o * NI] - m);
    const float inv = 1.f / s;
    float* outp = cbuf + bb * (NO * NI) + i;
    for (int o = 0; o < NO; ++o) outp[o * NI] = __expf(col[o * NI] - m) * inv;
}

extern "C" void kernel_launch(void* const* d_in, const int* in_sizes, int n_in,
                              void* d_out, int out_size, void* d_ws, size_t ws_size,
                              hipStream_t stream) {
    (void)in_sizes; (void)n_in; (void)out_size; (void)ws_size;
    const float* x      = (const float*)d_in[0];
    const float* conv_w = (const float*)d_in[1];
    const float* conv_b = (const float*)d_in[2];
    const float* pcap_w = (const float*)d_in[3];
    const float* pcap_b = (const float*)d_in[4];
    const float* W      = (const float*)d_in[5];
    float* out = (float*)d_out;
    float* ws  = (float*)d_ws;
    float* h   = ws + WS_H;
    float* u   = ws + WS_U;
    float* bbf = ws + WS_BB;
    float* cbf = ws + WS_CB;
    float* sp  = ws + WS_SP;
    float* v   = ws + WS_V;
    float* pp  = ws + WS_PP;   // overlaps bbf (dead until routing)
    float* wT  = ws + WS_WT;   // overlaps cbf (dead until routing)

    transpose_w_kernel<<<dim3(256, 4), 256, 0, stream>>>(pcap_w, wT);
    conv1_kernel<<<dim3(64, 16), 256, 0, stream>>>(x, conv_w, conv_b, h);
    conv2_partial_kernel<<<dim3(32, 4, 8), 256, 0, stream>>>(h, wT, pp);
    reduce_bias_squash_kernel<<<512, 256, 0, stream>>>(pp, pcap_b, u);
    // routing iter 0 (c uniform = 1/100)
    r_weighted_kernel<1><<<dim3(100, 16), 256, 0, stream>>>(W, u, nullptr, sp);
    squash_v_kernel<<<400, 256, 0, stream>>>(sp, v);
    r_logits_kernel<0><<<dim3(100, 16), 256, 0, stream>>>(W, u, v, bbf);
    // routing iter 1
    softmax_kernel<<<512, 256, 0, stream>>>(bbf, cbf);
    r_weighted_kernel<0><<<dim3(100, 16), 256, 0, stream>>>(W, u, cbf, sp);
    squash_v_kernel<<<400, 256, 0, stream>>>(sp, v);
    r_logits_kernel<1><<<dim3(100, 16), 256, 0, stream>>>(W, u, v, bbf);
    // routing iter 2
    softmax_kernel<<<512, 256, 0, stream>>>(bbf, cbf);
    r_weighted_kernel<0><<<dim3(100, 16), 256, 0, stream>>>(W, u, cbf, sp);
    squash_v_kernel<<<400, 256, 0, stream>>>(sp, out);
}

// Round 6
// 1840.581 us; speedup vs baseline: 1.0273x; 1.0273x over previous
//
#include <hip/hip_runtime.h>

#define NB 64
#define NO 100
#define NI 2048
#define ND 16
#define NK 8

// ws layout (float offsets)
#define WS_H    0            // h: 64*256*24*24 = 9437184
#define WS_U    9437184      // u: 64*2048*8 = 1048576
#define WS_BB   10485760     // b logits: 64*100*2048 = 13107200  (pp overlaps here pre-routing)
#define WS_CB   23592960     // c: 13107200                        (wT overlaps here pre-routing)
#define WS_SP   36700160     // s partials: 100*16*64*16 = 1638400
#define WS_V    38338560     // v: 64*100*16 = 102400
// total 38440960 floats = 153.8 MB
#define WS_PP   WS_BB        // conv2 partials: 8*64*256*64 = 8388608
#define WS_WT   WS_CB        // wT: 256*81*256 = 5308416

// ---------------- conv1: [64,3,32,32] -> relu -> [64,256,24,24] ----------------
__global__ __launch_bounds__(256) void conv1_kernel(const float* __restrict__ x,
        const float* __restrict__ w, const float* __restrict__ bias,
        float* __restrict__ h) {
    const int b = blockIdx.x;
    const int ocg = blockIdx.y;          // 16 oc per block
    __shared__ float xl[3 * 32 * 32];
    __shared__ float wl[16 * 243];
    const int tid = threadIdx.x;
    for (int idx = tid; idx < 3072; idx += 256) xl[idx] = x[b * 3072 + idx];
    for (int idx = tid; idx < 16 * 243; idx += 256)
        wl[idx] = w[ocg * 16 * 243 + idx];
    __syncthreads();
    const int lane = tid & 63;
    const int wg = tid >> 6;             // 0..3 -> 4 oc each
    float acc[4][9];
    #pragma unroll
    for (int jj = 0; jj < 4; ++jj) {
        float bv = bias[ocg * 16 + wg * 4 + jj];
        #pragma unroll
        for (int j = 0; j < 9; ++j) acc[jj][j] = bv;
    }
    int xbase[9];
    #pragma unroll
    for (int j = 0; j < 9; ++j) {
        int p = lane + 64 * j;           // 576 positions exactly
        xbase[j] = (p / 24) * 32 + (p % 24);
    }
    for (int ic = 0; ic < 3; ++ic)
        for (int ky = 0; ky < 9; ++ky) {
            #pragma unroll
            for (int kx = 0; kx < 9; ++kx) {
                float wv[4];
                #pragma unroll
                for (int jj = 0; jj < 4; ++jj)
                    wv[jj] = wl[(wg * 4 + jj) * 243 + ic * 81 + ky * 9 + kx];
                #pragma unroll
                for (int j = 0; j < 9; ++j) {
                    float xv = xl[ic * 1024 + xbase[j] + ky * 32 + kx];
                    #pragma unroll
                    for (int jj = 0; jj < 4; ++jj)
                        acc[jj][j] = fmaf(xv, wv[jj], acc[jj][j]);
                }
            }
        }
    #pragma unroll
    for (int jj = 0; jj < 4; ++jj) {
        int oc = ocg * 16 + wg * 4 + jj;
        #pragma unroll
        for (int j = 0; j < 9; ++j) {
            int p = lane + 64 * j;
            h[(b * 256 + oc) * 576 + p] = fmaxf(acc[jj][j], 0.f);
        }
    }
}

// ---------------- transpose pcap_w -> wT[ic][kk][oc] ----------------
__global__ __launch_bounds__(256) void transpose_w_kernel(const float* __restrict__ w,
        float* __restrict__ wT) {
    const int ic = blockIdx.x;           // 0..255
    const int ocq = blockIdx.y;          // 0..3 (64 oc each)
    __shared__ float tl[64][85];         // pad 85: gcd(21,32)=1, conflict-free
    const int tid = threadIdx.x;
    for (int f = tid; f < 5184; f += 256) {
        int oc = f / 81, kk = f % 81;
        tl[oc][kk] = w[(size_t)(ocq * 64 + oc) * 20736 + ic * 81 + kk];
    }
    __syncthreads();
    for (int f = tid; f < 5184; f += 256) {
        int kk = f >> 6, oc = f & 63;
        wT[((size_t)ic * 81 + kk) * 256 + ocq * 64 + oc] = tl[oc][kk];
    }
}

// ---------------- conv2 partial: K-split implicit GEMM ----------------
// block: 64 oc x 128 pos (2 batches) x 32-ic slice. thread: 8 oc x 4 pos.
// NOTE round-5 post-mortem: __launch_bounds__(256,4) capped VGPRs at 64 ->
// inner-loop scratch spills -> 937MB HBM WRITE (28x amplification). No cap:
// let the allocator keep staging temps + acc[8][4] in registers.
__global__ __launch_bounds__(256) void conv2_partial_kernel(
        const float* __restrict__ h, const float* __restrict__ wT,
        float* __restrict__ pp) {
    const int bpair = blockIdx.x;        // 0..31
    const int ocb = blockIdx.y;          // 0..3  (64 oc)
    const int ks = blockIdx.z;           // 0..7  (32 ic)
    __shared__ __align__(16) float wl[81 * 64];   // [kk][oc] linear
    __shared__ __align__(16) float xl[2 * 576];   // [bhalf][24*24]
    const int tid = threadIdx.x;
    const int ocg = tid & 7;             // 8 oc groups of 8
    const int posg = tid >> 3;           // 0..31
    const int bh = posg >> 4;            // batch half
    const int sub = posg & 15;           // pos chunk: pos = 4*sub + p
    const int oy = sub >> 1;             // output row 0..7
    const int ox0 = (sub & 1) * 4;       // output col base 0 or 4
    float acc[8][4];
    #pragma unroll
    for (int j = 0; j < 8; ++j)
        #pragma unroll
        for (int p = 0; p < 4; ++p) acc[j][p] = 0.f;
    const int ic0 = ks * 32;
    #pragma unroll 1
    for (int ic = ic0; ic < ic0 + 32; ++ic) {
        __syncthreads();
        // stage weights: 81 rows x 64 oc = 1296 float4, coalesced, LDS-linear
        const float4* wsrc = (const float4*)(wT + ((size_t)ic * 81) * 256 + ocb * 64);
        for (int it = tid; it < 1296; it += 256)
            ((float4*)wl)[it] = wsrc[(it >> 4) * 64 + (it & 15)];
        // stage x: 2 batches x 576 = 288 float4
        for (int it = tid; it < 288; it += 256) {
            int b2 = (it >= 144);
            int idx = it - b2 * 144;
            ((float4*)xl)[it] =
                ((const float4*)(h + ((size_t)(bpair * 2 + b2) * 256 + ic) * 576))[idx];
        }
        __syncthreads();
        const float* xb = xl + bh * 576;
        #pragma unroll
        for (int ky = 0; ky < 9; ++ky) {
            const float* xrow = xb + (2 * oy + ky) * 24 + 2 * ox0;
            #pragma unroll
            for (int kx = 0; kx < 9; ++kx) {
                const int kk = ky * 9 + kx;
                const float4 wa = *(const float4*)&wl[kk * 64 + ocg * 8];
                const float4 wb = *(const float4*)&wl[kk * 64 + ocg * 8 + 4];
                float xv[4];
                #pragma unroll
                for (int p = 0; p < 4; ++p) xv[p] = xrow[2 * p + kx];
                #pragma unroll
                for (int p = 0; p < 4; ++p) {
                    acc[0][p] = fmaf(wa.x, xv[p], acc[0][p]);
                    acc[1][p] = fmaf(wa.y, xv[p], acc[1][p]);
                    acc[2][p] = fmaf(wa.z, xv[p], acc[2][p]);
                    acc[3][p] = fmaf(wa.w, xv[p], acc[3][p]);
                    acc[4][p] = fmaf(wb.x, xv[p], acc[4][p]);
                    acc[5][p] = fmaf(wb.y, xv[p], acc[5][p]);
                    acc[6][p] = fmaf(wb.z, xv[p], acc[6][p]);
                    acc[7][p] = fmaf(wb.w, xv[p], acc[7][p]);
                }
            }
        }
    }
    const int b = bpair * 2 + bh;
    #pragma unroll
    for (int j = 0; j < 8; ++j) {
        const int oc = ocb * 64 + ocg * 8 + j;
        float4 st;
        st.x = acc[j][0]; st.y = acc[j][1]; st.z = acc[j][2]; st.w = acc[j][3];
        // pos = 4*sub + p, p contiguous -> one dwordx4 per j (16B aligned)
        *(float4*)&pp[(((size_t)ks * 64 + b) * 256 + oc) * 64 + 4 * sub] = st;
    }
}

// -------- reduce partials over ks, +bias, squash capsule rows of 8 -> u --------
__global__ __launch_bounds__(256) void reduce_bias_squash_kernel(
        const float* __restrict__ pp, const float* __restrict__ bias,
        float* __restrict__ u) {
    const int cap = blockIdx.x * 256 + threadIdx.x;   // 131072 capsules
    const int b = cap >> 11;
    const int rem = cap & 2047;
    const int oc = rem >> 3;
    const int oy = rem & 7;
    float4 sa = {0.f, 0.f, 0.f, 0.f}, sb = {0.f, 0.f, 0.f, 0.f};
    #pragma unroll
    for (int ks = 0; ks < 8; ++ks) {
        const float4* p4 = (const float4*)&pp[(((size_t)ks * 64 + b) * 256 + oc) * 64 + oy * 8];
        float4 a = p4[0], c = p4[1];
        sa.x += a.x; sa.y += a.y; sa.z += a.z; sa.w += a.w;
        sb.x += c.x; sb.y += c.y; sb.z += c.z; sb.w += c.w;
    }
    const float bv = bias[oc];
    sa.x += bv; sa.y += bv; sa.z += bv; sa.w += bv;
    sb.x += bv; sb.y += bv; sb.z += bv; sb.w += bv;
    float s2 = sa.x * sa.x + sa.y * sa.y + sa.z * sa.z + sa.w * sa.w
             + sb.x * sb.x + sb.y * sb.y + sb.z * sb.z + sb.w * sb.w;
    float scale = (s2 / (1.f + s2)) / sqrtf(s2 + 1e-8f);
    sa.x *= scale; sa.y *= scale; sa.z *= scale; sa.w *= scale;
    sb.x *= scale; sb.y *= scale; sb.z *= scale; sb.w *= scale;
    float4* up = (float4*)&u[(size_t)cap * 8];
    up[0] = sa;
    up[1] = sb;
}

// -------- weighted sum: s_part[o][st][b][d] = sum_i c[b,o,i]*u_hat[b,o,i,d] --------
template <int UNIFORM>
__global__ __launch_bounds__(256) void r_weighted_kernel(
        const float* __restrict__ W, const float* __restrict__ u,
        const float* __restrict__ cbuf, float* __restrict__ sp) {
    const int o = blockIdx.x;
    const int st = blockIdx.y;                 // 16 supertiles of 128 i
    __shared__ __align__(16) float Wl[16 * 128];   // [ii][d][k]
    __shared__ __align__(16) float ul[64 * 128];   // [b][ii][k]
    __shared__ float cl[64 * 16];                  // [b][ii]
    const int tid = threadIdx.x;
    const int d = tid & 15;
    const int bg = tid >> 4;
    float acc[4] = {0.f, 0.f, 0.f, 0.f};
    for (int sub = 0; sub < 8; ++sub) {
        const int i0 = st * 128 + sub * 16;
        __syncthreads();
        for (int idx = tid; idx < 2048; idx += 256)
            Wl[idx] = W[o * 262144 + i0 * 128 + idx];
        for (int idx = tid; idx < 8192; idx += 256) {
            int bb = idx >> 7, r = idx & 127;
            ul[idx] = u[bb * 16384 + i0 * 8 + r];
        }
        if (!UNIFORM) {
            for (int idx = tid; idx < 1024; idx += 256) {
                int bb = idx >> 4, ii = idx & 15;
                cl[idx] = cbuf[bb * (NO * NI) + o * NI + i0 + ii];
            }
        }
        __syncthreads();
        for (int ii = 0; ii < 16; ++ii) {
            const float4 wa = *(const float4*)&Wl[ii * 128 + d * 8];
            const float4 wb = *(const float4*)&Wl[ii * 128 + d * 8 + 4];
            #pragma unroll
            for (int j = 0; j < 4; ++j) {
                const int bb = bg + 16 * j;
                const float4 ua = *(const float4*)&ul[bb * 128 + ii * 8];
                const float4 ub = *(const float4*)&ul[bb * 128 + ii * 8 + 4];
                float uh = wa.x * ua.x + wa.y * ua.y + wa.z * ua.z + wa.w * ua.w
                         + wb.x * ub.x + wb.y * ub.y + wb.z * ub.z + wb.w * ub.w;
                float cv = UNIFORM ? 0.01f : cl[bb * 16 + ii];
                acc[j] = fmaf(cv, uh, acc[j]);
            }
        }
    }
    #pragma unroll
    for (int j = 0; j < 4; ++j) {
        const int bb = bg + 16 * j;
        sp[((o * 16 + st) * 64 + bb) * 16 + d] = acc[j];
    }
}

// -------- reduce partials over st, squash over d, write v (or final out) --------
__global__ __launch_bounds__(256) void squash_v_kernel(const float* __restrict__ sp,
        float* __restrict__ dest) {
    const int t = blockIdx.x * 256 + threadIdx.x;  // 102400 slots
    const int d = t & 15;
    const int cap = t >> 4;                        // o*64 + b
    const int o = cap >> 6;
    const int bb = cap & 63;
    float s = 0.f;
    #pragma unroll
    for (int st = 0; st < 16; ++st)
        s += sp[((o * 16 + st) * 64 + bb) * 16 + d];
    float s2 = s * s;
    #pragma unroll
    for (int off = 1; off < 16; off <<= 1)
        s2 += __shfl_xor(s2, off, 16);
    float scale = (s2 / (1.f + s2)) / sqrtf(s2 + 1e-8f);
    dest[(bb * NO + o) * ND + d] = s * scale;
}

// -------- logits: b[b,o,i] (+)= sum_d u_hat[b,o,i,d] * v[b,o,d] --------
template <int ADD>
__global__ __launch_bounds__(256) void r_logits_kernel(
        const float* __restrict__ W, const float* __restrict__ u,
        const float* __restrict__ v, float* __restrict__ bbuf) {
    const int o = blockIdx.x;
    const int st = blockIdx.y;
    __shared__ __align__(16) float Wl[16 * 128];
    __shared__ __align__(16) float ul[64 * 128];
    __shared__ float vl[64 * 16];
    const int tid = threadIdx.x;
    const int ii = tid & 15;
    const int bg = tid >> 4;
    for (int idx = tid; idx < 1024; idx += 256) {
        int bb = idx >> 4, dd = idx & 15;
        vl[idx] = v[(bb * NO + o) * ND + dd];
    }
    for (int sub = 0; sub < 8; ++sub) {
        const int i0 = st * 128 + sub * 16;
        __syncthreads();
        for (int idx = tid; idx < 2048; idx += 256)
            Wl[idx] = W[o * 262144 + i0 * 128 + idx];
        for (int idx = tid; idx < 8192; idx += 256) {
            int bb = idx >> 7, r = idx & 127;
            ul[idx] = u[bb * 16384 + i0 * 8 + r];
        }
        __syncthreads();
        float4 ua[4], ub[4];
        #pragma unroll
        for (int j = 0; j < 4; ++j) {
            const int bb = bg + 16 * j;
            ua[j] = *(const float4*)&ul[bb * 128 + ii * 8];
            ub[j] = *(const float4*)&ul[bb * 128 + ii * 8 + 4];
        }
        float tmp[4] = {0.f, 0.f, 0.f, 0.f};
        for (int dd = 0; dd < 16; ++dd) {
            const float4 wa = *(const float4*)&Wl[ii * 128 + dd * 8];
            const float4 wb = *(const float4*)&Wl[ii * 128 + dd * 8 + 4];
            #pragma unroll
            for (int j = 0; j < 4; ++j) {
                float uh = wa.x * ua[j].x + wa.y * ua[j].y + wa.z * ua[j].z + wa.w * ua[j].w
                         + wb.x * ub[j].x + wb.y * ub[j].y + wb.z * ub[j].z + wb.w * ub[j].w;
                tmp[j] = fmaf(uh, vl[(bg + 16 * j) * 16 + dd], tmp[j]);
            }
        }
        #pragma unroll
        for (int j = 0; j < 4; ++j) {
            const int bb = bg + 16 * j;
            const int addr = bb * (NO * NI) + o * NI + i0 + ii;
            bbuf[addr] = (ADD ? bbuf[addr] : 0.f) + tmp[j];
        }
    }
}

// -------- softmax over o (axis=1) of b -> c --------
__global__ __launch_bounds__(256) void softmax_kernel(const float* __restrict__ bbuf,
        float* __restrict__ cbuf) {
    const int bb = blockIdx.x >> 3;
    const int i = (blockIdx.x & 7) * 256 + threadIdx.x;
    const float* col = bbuf + bb * (NO * NI) + i;
    float m = -1e30f;
    for (int o = 0; o < NO; ++o) m = fmaxf(m, col[o * NI]);
    float s = 0.f;
    for (int o = 0; o < NO; ++o) s += __expf(col[o * NI] - m);
    const float inv = 1.f / s;
    float* outp = cbuf + bb * (NO * NI) + i;
    for (int o = 0; o < NO; ++o) outp[o * NI] = __expf(col[o * NI] - m) * inv;
}

extern "C" void kernel_launch(void* const* d_in, const int* in_sizes, int n_in,
                              void* d_out, int out_size, void* d_ws, size_t ws_size,
                              hipStream_t stream) {
    (void)in_sizes; (void)n_in; (void)out_size; (void)ws_size;
    const float* x      = (const float*)d_in[0];
    const float* conv_w = (const float*)d_in[1];
    const float* conv_b = (const float*)d_in[2];
    const float* pcap_w = (const float*)d_in[3];
    const float* pcap_b = (const float*)d_in[4];
    const float* W      = (const float*)d_in[5];
    float* out = (float*)d_out;
    float* ws  = (float*)d_ws;
    float* h   = ws + WS_H;
    float* u   = ws + WS_U;
    float* bbf = ws + WS_BB;
    float* cbf = ws + WS_CB;
    float* sp  = ws + WS_SP;
    float* v   = ws + WS_V;
    float* pp  = ws + WS_PP;   // overlaps bbf (dead until routing)
    float* wT  = ws + WS_WT;   // overlaps cbf (dead until routing)

    transpose_w_kernel<<<dim3(256, 4), 256, 0, stream>>>(pcap_w, wT);
    conv1_kernel<<<dim3(64, 16), 256, 0, stream>>>(x, conv_w, conv_b, h);
    conv2_partial_kernel<<<dim3(32, 4, 8), 256, 0, stream>>>(h, wT, pp);
    reduce_bias_squash_kernel<<<512, 256, 0, stream>>>(pp, pcap_b, u);
    // routing iter 0 (c uniform = 1/100)
    r_weighted_kernel<1><<<dim3(100, 16), 256, 0, stream>>>(W, u, nullptr, sp);
    squash_v_kernel<<<400, 256, 0, stream>>>(sp, v);
    r_logits_kernel<0><<<dim3(100, 16), 256, 0, stream>>>(W, u, v, bbf);
    // routing iter 1
    softmax_kernel<<<512, 256, 0, stream>>>(bbf, cbf);
    r_weighted_kernel<0><<<dim3(100, 16), 256, 0, stream>>>(W, u, cbf, sp);
    squash_v_kernel<<<400, 256, 0, stream>>>(sp, v);
    r_logits_kernel<1><<<dim3(100, 16), 256, 0, stream>>>(W, u, v, bbf);
    // routing iter 2
    softmax_kernel<<<512, 256, 0, stream>>>(bbf, cbf);
    r_weighted_kernel<0><<<dim3(100, 16), 256, 0, stream>>>(W, u, cbf, sp);
    squash_v_kernel<<<400, 256, 0, stream>>>(sp, out);
}

// Round 8
// 1813.667 us; speedup vs baseline: 1.0425x; 1.0148x over previous
//
#include <hip/hip_runtime.h>

#define NB 64
#define NO 100
#define NI 2048
#define ND 16
#define NK 8

// ws layout (float offsets)
#define WS_H    0            // h: 64*256*24*24 = 9437184
#define WS_U    9437184      // u: 64*2048*8 = 1048576
#define WS_BB   10485760     // b logits: 64*100*2048 = 13107200  (pp overlaps here pre-routing)
#define WS_CB   23592960     // c: 13107200                        (wT overlaps here pre-routing)
#define WS_SP   36700160     // s partials: 100*16*64*16 = 1638400
#define WS_V    38338560     // v: 64*100*16 = 102400
// total 38440960 floats = 153.8 MB
#define WS_PP   WS_BB        // conv2 partials: 8*64*256*64 = 8388608
#define WS_WT   WS_CB        // wT: 256*81*256 = 5308416

// ---------------- conv1: [64,3,32,32] -> relu -> [64,256,24,24] ----------------
__global__ __launch_bounds__(256) void conv1_kernel(const float* __restrict__ x,
        const float* __restrict__ w, const float* __restrict__ bias,
        float* __restrict__ h) {
    const int b = blockIdx.x;
    const int ocg = blockIdx.y;          // 16 oc per block
    __shared__ float xl[3 * 32 * 32];
    __shared__ float wl[16 * 243];
    const int tid = threadIdx.x;
    for (int idx = tid; idx < 3072; idx += 256) xl[idx] = x[b * 3072 + idx];
    for (int idx = tid; idx < 16 * 243; idx += 256)
        wl[idx] = w[ocg * 16 * 243 + idx];
    __syncthreads();
    const int lane = tid & 63;
    const int wg = tid >> 6;             // 0..3 -> 4 oc each
    float acc[4][9];
    #pragma unroll
    for (int jj = 0; jj < 4; ++jj) {
        float bv = bias[ocg * 16 + wg * 4 + jj];
        #pragma unroll
        for (int j = 0; j < 9; ++j) acc[jj][j] = bv;
    }
    int xbase[9];
    #pragma unroll
    for (int j = 0; j < 9; ++j) {
        int p = lane + 64 * j;           // 576 positions exactly
        xbase[j] = (p / 24) * 32 + (p % 24);
    }
    for (int ic = 0; ic < 3; ++ic)
        for (int ky = 0; ky < 9; ++ky) {
            #pragma unroll
            for (int kx = 0; kx < 9; ++kx) {
                float wv[4];
                #pragma unroll
                for (int jj = 0; jj < 4; ++jj)
                    wv[jj] = wl[(wg * 4 + jj) * 243 + ic * 81 + ky * 9 + kx];
                #pragma unroll
                for (int j = 0; j < 9; ++j) {
                    float xv = xl[ic * 1024 + xbase[j] + ky * 32 + kx];
                    #pragma unroll
                    for (int jj = 0; jj < 4; ++jj)
                        acc[jj][j] = fmaf(xv, wv[jj], acc[jj][j]);
                }
            }
        }
    #pragma unroll
    for (int jj = 0; jj < 4; ++jj) {
        int oc = ocg * 16 + wg * 4 + jj;
        #pragma unroll
        for (int j = 0; j < 9; ++j) {
            int p = lane + 64 * j;
            h[(b * 256 + oc) * 576 + p] = fmaxf(acc[jj][j], 0.f);
        }
    }
}

// ---------------- transpose pcap_w -> wT[ic][kk][oc] ----------------
__global__ __launch_bounds__(256) void transpose_w_kernel(const float* __restrict__ w,
        float* __restrict__ wT) {
    const int ic = blockIdx.x;           // 0..255
    const int ocq = blockIdx.y;          // 0..3 (64 oc each)
    __shared__ float tl[64][85];         // pad 85: gcd(21,32)=1, conflict-free
    const int tid = threadIdx.x;
    for (int f = tid; f < 5184; f += 256) {
        int oc = f / 81, kk = f % 81;
        tl[oc][kk] = w[(size_t)(ocq * 64 + oc) * 20736 + ic * 81 + kk];
    }
    __syncthreads();
    for (int f = tid; f < 5184; f += 256) {
        int kk = f >> 6, oc = f & 63;
        wT[((size_t)ic * 81 + kk) * 256 + ocq * 64 + oc] = tl[oc][kk];
    }
}

// ---------------- conv2 partial: K-split implicit GEMM ----------------
// block: 64 oc x 128 pos (2 batches) x 32-ic slice. thread: 8 oc x 4 pos.
// Round-5 lesson: no launch_bounds reg cap (64-VGPR cap -> scratch spills).
// Round-6 lesson: kernel is VALU-issue bound (VALUBusy 62%, HBM 2.5%) -- the
// 4 scalar ds_read_b32 x-loads per kk serialized against the FMAs. Fix:
// register-cache 16 x floats per (ic,ky) via 4 ds_read_b128; all kx/p x
// accesses become static register indices.
__global__ __launch_bounds__(256) void conv2_partial_kernel(
        const float* __restrict__ h, const float* __restrict__ wT,
        float* __restrict__ pp) {
    const int bpair = blockIdx.x;        // 0..31
    const int ocb = blockIdx.y;          // 0..3  (64 oc)
    const int ks = blockIdx.z;           // 0..7  (32 ic)
    __shared__ __align__(16) float wl[81 * 64];   // [kk][oc] linear
    __shared__ __align__(16) float xl[2 * 576];   // [bhalf][24*24]
    const int tid = threadIdx.x;
    const int ocg = tid & 7;             // 8 oc groups of 8
    const int posg = tid >> 3;           // 0..31
    const int bh = posg >> 4;            // batch half
    const int sub = posg & 15;           // pos chunk: pos = 4*sub + p
    const int oy = sub >> 1;             // output row 0..7
    const int ox0 = (sub & 1) * 4;       // output col base 0 or 4
    float acc[8][4];
    #pragma unroll
    for (int j = 0; j < 8; ++j)
        #pragma unroll
        for (int p = 0; p < 4; ++p) acc[j][p] = 0.f;
    const int ic0 = ks * 32;
    #pragma unroll 1
    for (int ic = ic0; ic < ic0 + 32; ++ic) {
        __syncthreads();
        // stage weights: 81 rows x 64 oc = 1296 float4, coalesced, LDS-linear
        const float4* wsrc = (const float4*)(wT + ((size_t)ic * 81) * 256 + ocb * 64);
        for (int it = tid; it < 1296; it += 256)
            ((float4*)wl)[it] = wsrc[(it >> 4) * 64 + (it & 15)];
        // stage x: 2 batches x 576 = 288 float4
        for (int it = tid; it < 288; it += 256) {
            int b2 = (it >= 144);
            int idx = it - b2 * 144;
            ((float4*)xl)[it] =
                ((const float4*)(h + ((size_t)(bpair * 2 + b2) * 256 + ic) * 576))[idx];
        }
        __syncthreads();
        const float* xb = xl + bh * 576;
        #pragma unroll
        for (int ky = 0; ky < 9; ++ky) {
            // register-cache the 16-float x window for this (ic, ky):
            // input row 2*oy+ky, cols 2*ox0 .. 2*ox0+15 (needs 0..14).
            // (2*oy+ky)*24 + 2*ox0 is divisible by 4 -> 16B-aligned b128 reads.
            const float* xrow = xb + (2 * oy + ky) * 24 + 2 * ox0;
            float xreg[16];
            *(float4*)&xreg[0]  = *(const float4*)&xrow[0];
            *(float4*)&xreg[4]  = *(const float4*)&xrow[4];
            *(float4*)&xreg[8]  = *(const float4*)&xrow[8];
            *(float4*)&xreg[12] = *(const float4*)&xrow[12];
            #pragma unroll
            for (int kx = 0; kx < 9; ++kx) {
                const int kk = ky * 9 + kx;
                const float4 wa = *(const float4*)&wl[kk * 64 + ocg * 8];
                const float4 wb = *(const float4*)&wl[kk * 64 + ocg * 8 + 4];
                #pragma unroll
                for (int p = 0; p < 4; ++p) {
                    const float xv = xreg[2 * p + kx];   // static index after unroll
                    acc[0][p] = fmaf(wa.x, xv, acc[0][p]);
                    acc[1][p] = fmaf(wa.y, xv, acc[1][p]);
                    acc[2][p] = fmaf(wa.z, xv, acc[2][p]);
                    acc[3][p] = fmaf(wa.w, xv, acc[3][p]);
                    acc[4][p] = fmaf(wb.x, xv, acc[4][p]);
                    acc[5][p] = fmaf(wb.y, xv, acc[5][p]);
                    acc[6][p] = fmaf(wb.z, xv, acc[6][p]);
                    acc[7][p] = fmaf(wb.w, xv, acc[7][p]);
                }
            }
        }
    }
    const int b = bpair * 2 + bh;
    #pragma unroll
    for (int j = 0; j < 8; ++j) {
        const int oc = ocb * 64 + ocg * 8 + j;
        float4 st;
        st.x = acc[j][0]; st.y = acc[j][1]; st.z = acc[j][2]; st.w = acc[j][3];
        // pos = 4*sub + p, p contiguous -> one dwordx4 per j (16B aligned)
        *(float4*)&pp[(((size_t)ks * 64 + b) * 256 + oc) * 64 + 4 * sub] = st;
    }
}

// -------- reduce partials over ks, +bias, squash capsule rows of 8 -> u --------
__global__ __launch_bounds__(256) void reduce_bias_squash_kernel(
        const float* __restrict__ pp, const float* __restrict__ bias,
        float* __restrict__ u) {
    const int cap = blockIdx.x * 256 + threadIdx.x;   // 131072 capsules
    const int b = cap >> 11;
    const int rem = cap & 2047;
    const int oc = rem >> 3;
    const int oy = rem & 7;
    float4 sa = {0.f, 0.f, 0.f, 0.f}, sb = {0.f, 0.f, 0.f, 0.f};
    #pragma unroll
    for (int ks = 0; ks < 8; ++ks) {
        const float4* p4 = (const float4*)&pp[(((size_t)ks * 64 + b) * 256 + oc) * 64 + oy * 8];
        float4 a = p4[0], c = p4[1];
        sa.x += a.x; sa.y += a.y; sa.z += a.z; sa.w += a.w;
        sb.x += c.x; sb.y += c.y; sb.z += c.z; sb.w += c.w;
    }
    const float bv = bias[oc];
    sa.x += bv; sa.y += bv; sa.z += bv; sa.w += bv;
    sb.x += bv; sb.y += bv; sb.z += bv; sb.w += bv;
    float s2 = sa.x * sa.x + sa.y * sa.y + sa.z * sa.z + sa.w * sa.w
             + sb.x * sb.x + sb.y * sb.y + sb.z * sb.z + sb.w * sb.w;
    float scale = (s2 / (1.f + s2)) / sqrtf(s2 + 1e-8f);
    sa.x *= scale; sa.y *= scale; sa.z *= scale; sa.w *= scale;
    sb.x *= scale; sb.y *= scale; sb.z *= scale; sb.w *= scale;
    float4* up = (float4*)&u[(size_t)cap * 8];
    up[0] = sa;
    up[1] = sb;
}

// -------- weighted sum: s_part[o][st][b][d] = sum_i c[b,o,i]*u_hat[b,o,i,d] --------
template <int UNIFORM>
__global__ __launch_bounds__(256) void r_weighted_kernel(
        const float* __restrict__ W, const float* __restrict__ u,
        const float* __restrict__ cbuf, float* __restrict__ sp) {
    const int o = blockIdx.x;
    const int st = blockIdx.y;                 // 16 supertiles of 128 i
    __shared__ __align__(16) float Wl[16 * 128];   // [ii][d][k]
    __shared__ __align__(16) float ul[64 * 128];   // [b][ii][k]
    __shared__ float cl[64 * 16];                  // [b][ii]
    const int tid = threadIdx.x;
    const int d = tid & 15;
    const int bg = tid >> 4;
    float acc[4] = {0.f, 0.f, 0.f, 0.f};
    for (int sub = 0; sub < 8; ++sub) {
        const int i0 = st * 128 + sub * 16;
        __syncthreads();
        for (int idx = tid; idx < 2048; idx += 256)
            Wl[idx] = W[o * 262144 + i0 * 128 + idx];
        for (int idx = tid; idx < 8192; idx += 256) {
            int bb = idx >> 7, r = idx & 127;
            ul[idx] = u[bb * 16384 + i0 * 8 + r];
        }
        if (!UNIFORM) {
            for (int idx = tid; idx < 1024; idx += 256) {
                int bb = idx >> 4, ii = idx & 15;
                cl[idx] = cbuf[bb * (NO * NI) + o * NI + i0 + ii];
            }
        }
        __syncthreads();
        for (int ii = 0; ii < 16; ++ii) {
            const float4 wa = *(const float4*)&Wl[ii * 128 + d * 8];
            const float4 wb = *(const float4*)&Wl[ii * 128 + d * 8 + 4];
            #pragma unroll
            for (int j = 0; j < 4; ++j) {
                const int bb = bg + 16 * j;
                const float4 ua = *(const float4*)&ul[bb * 128 + ii * 8];
                const float4 ub = *(const float4*)&ul[bb * 128 + ii * 8 + 4];
                float uh = wa.x * ua.x + wa.y * ua.y + wa.z * ua.z + wa.w * ua.w
                         + wb.x * ub.x + wb.y * ub.y + wb.z * ub.z + wb.w * ub.w;
                float cv = UNIFORM ? 0.01f : cl[bb * 16 + ii];
                acc[j] = fmaf(cv, uh, acc[j]);
            }
        }
    }
    #pragma unroll
    for (int j = 0; j < 4; ++j) {
        const int bb = bg + 16 * j;
        sp[((o * 16 + st) * 64 + bb) * 16 + d] = acc[j];
    }
}

// -------- reduce partials over st, squash over d, write v (or final out) --------
__global__ __launch_bounds__(256) void squash_v_kernel(const float* __restrict__ sp,
        float* __restrict__ dest) {
    const int t = blockIdx.x * 256 + threadIdx.x;  // 102400 slots
    const int d = t & 15;
    const int cap = t >> 4;                        // o*64 + b
    const int o = cap >> 6;
    const int bb = cap & 63;
    float s = 0.f;
    #pragma unroll
    for (int st = 0; st < 16; ++st)
        s += sp[((o * 16 + st) * 64 + bb) * 16 + d];
    float s2 = s * s;
    #pragma unroll
    for (int off = 1; off < 16; off <<= 1)
        s2 += __shfl_xor(s2, off, 16);
    float scale = (s2 / (1.f + s2)) / sqrtf(s2 + 1e-8f);
    dest[(bb * NO + o) * ND + d] = s * scale;
}

// -------- logits: b[b,o,i] (+)= sum_d u_hat[b,o,i,d] * v[b,o,d] --------
template <int ADD>
__global__ __launch_bounds__(256) void r_logits_kernel(
        const float* __restrict__ W, const float* __restrict__ u,
        const float* __restrict__ v, float* __restrict__ bbuf) {
    const int o = blockIdx.x;
    const int st = blockIdx.y;
    __shared__ __align__(16) float Wl[16 * 128];
    __shared__ __align__(16) float ul[64 * 128];
    __shared__ float vl[64 * 16];
    const int tid = threadIdx.x;
    const int ii = tid & 15;
    const int bg = tid >> 4;
    for (int idx = tid; idx < 1024; idx += 256) {
        int bb = idx >> 4, dd = idx & 15;
        vl[idx] = v[(bb * NO + o) * ND + dd];
    }
    for (int sub = 0; sub < 8; ++sub) {
        const int i0 = st * 128 + sub * 16;
        __syncthreads();
        for (int idx = tid; idx < 2048; idx += 256)
            Wl[idx] = W[o * 262144 + i0 * 128 + idx];
        for (int idx = tid; idx < 8192; idx += 256) {
            int bb = idx >> 7, r = idx & 127;
            ul[idx] = u[bb * 16384 + i0 * 8 + r];
        }
        __syncthreads();
        float4 ua[4], ub[4];
        #pragma unroll
        for (int j = 0; j < 4; ++j) {
            const int bb = bg + 16 * j;
            ua[j] = *(const float4*)&ul[bb * 128 + ii * 8];
            ub[j] = *(const float4*)&ul[bb * 128 + ii * 8 + 4];
        }
        float tmp[4] = {0.f, 0.f, 0.f, 0.f};
        for (int dd = 0; dd < 16; ++dd) {
            const float4 wa = *(const float4*)&Wl[ii * 128 + dd * 8];
            const float4 wb = *(const float4*)&Wl[ii * 128 + dd * 8 + 4];
            #pragma unroll
            for (int j = 0; j < 4; ++j) {
                float uh = wa.x * ua[j].x + wa.y * ua[j].y + wa.z * ua[j].z + wa.w * ua[j].w
                         + wb.x * ub[j].x + wb.y * ub[j].y + wb.z * ub[j].z + wb.w * ub[j].w;
                tmp[j] = fmaf(uh, vl[(bg + 16 * j) * 16 + dd], tmp[j]);
            }
        }
        #pragma unroll
        for (int j = 0; j < 4; ++j) {
            const int bb = bg + 16 * j;
            const int addr = bb * (NO * NI) + o * NI + i0 + ii;
            bbuf[addr] = (ADD ? bbuf[addr] : 0.f) + tmp[j];
        }
    }
}

// -------- softmax over o (axis=1) of b -> c --------
__global__ __launch_bounds__(256) void softmax_kernel(const float* __restrict__ bbuf,
        float* __restrict__ cbuf) {
    const int bb = blockIdx.x >> 3;
    const int i = (blockIdx.x & 7) * 256 + threadIdx.x;
    const float* col = bbuf + bb * (NO * NI) + i;
    float m = -1e30f;
    for (int o = 0; o < NO; ++o) m = fmaxf(m, col[o * NI]);
    float s = 0.f;
    for (int o = 0; o < NO; ++o) s += __expf(col[o * NI] - m);
    const float inv = 1.f / s;
    float* outp = cbuf + bb * (NO * NI) + i;
    for (int o = 0; o < NO; ++o) outp[o * NI] = __expf(col[o * NI] - m) * inv;
}

extern "C" void kernel_launch(void* const* d_in, const int* in_sizes, int n_in,
                              void* d_out, int out_size, void* d_ws, size_t ws_size,
                              hipStream_t stream) {
    (void)in_sizes; (void)n_in; (void)out_size; (void)ws_size;
    const float* x      = (const float*)d_in[0];
    const float* conv_w = (const float*)d_in[1];
    const float* conv_b = (const float*)d_in[2];
    const float* pcap_w = (const float*)d_in[3];
    const float* pcap_b = (const float*)d_in[4];
    const float* W      = (const float*)d_in[5];
    float* out = (float*)d_out;
    float* ws  = (float*)d_ws;
    float* h   = ws + WS_H;
    float* u   = ws + WS_U;
    float* bbf = ws + WS_BB;
    float* cbf = ws + WS_CB;
    float* sp  = ws + WS_SP;
    float* v   = ws + WS_V;
    float* pp  = ws + WS_PP;   // overlaps bbf (dead until routing)
    float* wT  = ws + WS_WT;   // overlaps cbf (dead until routing)

    transpose_w_kernel<<<dim3(256, 4), 256, 0, stream>>>(pcap_w, wT);
    conv1_kernel<<<dim3(64, 16), 256, 0, stream>>>(x, conv_w, conv_b, h);
    conv2_partial_kernel<<<dim3(32, 4, 8), 256, 0, stream>>>(h, wT, pp);
    reduce_bias_squash_kernel<<<512, 256, 0, stream>>>(pp, pcap_b, u);
    // routing iter 0 (c uniform = 1/100)
    r_weighted_kernel<1><<<dim3(100, 16), 256, 0, stream>>>(W, u, nullptr, sp);
    squash_v_kernel<<<400, 256, 0, stream>>>(sp, v);
    r_logits_kernel<0><<<dim3(100, 16), 256, 0, stream>>>(W, u, v, bbf);
    // routing iter 1
    softmax_kernel<<<512, 256, 0, stream>>>(bbf, cbf);
    r_weighted_kernel<0><<<dim3(100, 16), 256, 0, stream>>>(W, u, cbf, sp);
    squash_v_kernel<<<400, 256, 0, stream>>>(sp, v);
    r_logits_kernel<1><<<dim3(100, 16), 256, 0, stream>>>(W, u, v, bbf);
    // routing iter 2
    softmax_kernel<<<512, 256, 0, stream>>>(bbf, cbf);
    r_weighted_kernel<0><<<dim3(100, 16), 256, 0, stream>>>(W, u, cbf, sp);
    squash_v_kernel<<<400, 256, 0, stream>>>(sp, out);
}

// Round 9
// 1504.610 us; speedup vs baseline: 1.2566x; 1.2054x over previous
//
#include <hip/hip_runtime.h>

#define NB 64
#define NO 100
#define NI 2048
#define ND 16
#define NK 8

// ws layout (float offsets)
#define WS_H    0            // h_hi + h_lo: 2x 9437184 ushort = 9437184 floats
#define WS_U    9437184      // u: 64*2048*8 = 1048576
#define WS_BB   10485760     // b logits: 13107200 (pp overlaps here pre-routing)
#define WS_CB   23592960     // c: 13107200 (wB_hi/lo overlap here pre-routing)
#define WS_SP   36700160     // s partials: 1638400
#define WS_V    38338560     // v: 102400
#define WS_PP   WS_BB        // conv2 partials: 8*64*256*64 = 8388608 floats

typedef __attribute__((ext_vector_type(8))) short bf16x8;
typedef __attribute__((ext_vector_type(16))) float f32x16;

__device__ inline unsigned short f2bf(float x) {   // RNE float->bf16
    union { float f; unsigned u; } v; v.f = x;
    unsigned r = (v.u + 0x7FFFu + ((v.u >> 16) & 1u)) >> 16;
    return (unsigned short)r;
}
__device__ inline float bf2f(unsigned short h) {
    union { unsigned u; float f; } v; v.u = ((unsigned)h) << 16;
    return v.f;
}

// ---------------- conv1: [64,3,32,32] -> relu -> h_hi/h_lo bf16 [64,256,24,24] ----
__global__ __launch_bounds__(256) void conv1_kernel(const float* __restrict__ x,
        const float* __restrict__ w, const float* __restrict__ bias,
        unsigned short* __restrict__ h_hi, unsigned short* __restrict__ h_lo) {
    const int b = blockIdx.x;
    const int ocg = blockIdx.y;          // 16 oc per block
    __shared__ float xl[3 * 32 * 32];
    __shared__ float wl[16 * 243];
    const int tid = threadIdx.x;
    for (int idx = tid; idx < 3072; idx += 256) xl[idx] = x[b * 3072 + idx];
    for (int idx = tid; idx < 16 * 243; idx += 256)
        wl[idx] = w[ocg * 16 * 243 + idx];
    __syncthreads();
    const int lane = tid & 63;
    const int wg = tid >> 6;             // 0..3 -> 4 oc each
    float acc[4][9];
    #pragma unroll
    for (int jj = 0; jj < 4; ++jj) {
        float bv = bias[ocg * 16 + wg * 4 + jj];
        #pragma unroll
        for (int j = 0; j < 9; ++j) acc[jj][j] = bv;
    }
    int xbase[9];
    #pragma unroll
    for (int j = 0; j < 9; ++j) {
        int p = lane + 64 * j;           // 576 positions exactly
        xbase[j] = (p / 24) * 32 + (p % 24);
    }
    for (int ic = 0; ic < 3; ++ic)
        for (int ky = 0; ky < 9; ++ky) {
            #pragma unroll
            for (int kx = 0; kx < 9; ++kx) {
                float wv[4];
                #pragma unroll
                for (int jj = 0; jj < 4; ++jj)
                    wv[jj] = wl[(wg * 4 + jj) * 243 + ic * 81 + ky * 9 + kx];
                #pragma unroll
                for (int j = 0; j < 9; ++j) {
                    float xv = xl[ic * 1024 + xbase[j] + ky * 32 + kx];
                    #pragma unroll
                    for (int jj = 0; jj < 4; ++jj)
                        acc[jj][j] = fmaf(xv, wv[jj], acc[jj][j]);
                }
            }
        }
    #pragma unroll
    for (int jj = 0; jj < 4; ++jj) {
        int oc = ocg * 16 + wg * 4 + jj;
        #pragma unroll
        for (int j = 0; j < 9; ++j) {
            int p = lane + 64 * j;
            float v = fmaxf(acc[jj][j], 0.f);
            unsigned short hi = f2bf(v);
            unsigned short lo = f2bf(v - bf2f(hi));
            size_t o = (size_t)(b * 256 + oc) * 576 + p;
            h_hi[o] = hi;
            h_lo[o] = lo;
        }
    }
}

// ---- precompute wB_hi/lo[ic][ky][oc][16] bf16 (kx 0..8, pad 9..15 = 0) ----
__global__ __launch_bounds__(256) void wb_precompute_kernel(const float* __restrict__ w,
        unsigned short* __restrict__ wBhi, unsigned short* __restrict__ wBlo) {
    const int ic = blockIdx.x;           // 0..255
    const int ocq = blockIdx.y;          // 0..3 (64 oc each)
    __shared__ float tl[64][85];
    const int tid = threadIdx.x;
    for (int f = tid; f < 5184; f += 256) {
        int oc = f / 81, kk = f % 81;
        tl[oc][kk] = w[(size_t)(ocq * 64 + oc) * 20736 + ic * 81 + kk];
    }
    __syncthreads();
    for (int idx = tid; idx < 9216; idx += 256) {   // 9 ky * 64 oc * 16 kx
        int ky = idx >> 10;
        int rem = idx & 1023;
        int ocl = rem >> 4;
        int kx = rem & 15;
        float val = (kx < 9) ? tl[ocl][ky * 9 + kx] : 0.f;
        unsigned short hi = f2bf(val);
        unsigned short lo = f2bf(val - bf2f(hi));
        size_t dst = ((size_t)(ic * 9 + ky) * 256 + ocq * 64 + ocl) * 16 + kx;
        wBhi[dst] = hi;
        wBlo[dst] = lo;
    }
}

// ---------------- conv2 via MFMA (split-bf16): partials over ks ----------------
// block: 128 oc x 128 pos (2 batches) x 32 ic. 4 waves, each a 64x64 tile =
// 2x2 mfma_f32_32x32x16_bf16 tiles; K-chunk = (ic, ky) with kx padded 9->16.
// 3 MFMAs per tile-chunk: hi*hi + hi*lo + lo*hi (~fp32 precision).
__global__ __launch_bounds__(256) void conv2_mfma_kernel(
        const unsigned short* __restrict__ h_hi, const unsigned short* __restrict__ h_lo,
        const unsigned short* __restrict__ wBhi, const unsigned short* __restrict__ wBlo,
        float* __restrict__ pp) {
    const int bpair = blockIdx.x;        // 0..31
    const int ocb = blockIdx.y;          // 0..1  (128 oc)
    const int ks = blockIdx.z;           // 0..7  (32 ic)
    __shared__ __align__(16) unsigned short Ahi[128 * 16];
    __shared__ __align__(16) unsigned short Alo[128 * 16];
    __shared__ __align__(16) unsigned short Bhi[128 * 16];
    __shared__ __align__(16) unsigned short Blo[128 * 16];
    const int tid = threadIdx.x;
    const int lane = tid & 63;
    const int wid = tid >> 6;
    const int wr = wid >> 1, wc = wid & 1;        // wave tile origin (64x64)
    const int l31 = lane & 31, kh = lane >> 5;
    // B staging: thread -> (slot, role)
    const int slot = tid & 127;                    // blocal*64 + oy*8 + ox
    const int role = tid >> 7;                     // 0: hi, 1: lo
    const int oy = (slot >> 3) & 7;
    const int ox = slot & 7;
    const unsigned short* hsel = role ? h_lo : h_hi;
    const size_t hrow0 = ((size_t)(bpair * 2 + (slot >> 6)) * 256) * 576;

    f32x16 acc[2][2];
    #pragma unroll
    for (int m = 0; m < 2; ++m)
        #pragma unroll
        for (int n = 0; n < 2; ++n)
            #pragma unroll
            for (int r = 0; r < 16; ++r) acc[m][n][r] = 0.f;

    const int ic0 = ks * 32;
    for (int ic = ic0; ic < ic0 + 32; ++ic) {
        const size_t wb_ic = (size_t)ic * 9 * 4096;      // *256*16
        const size_t h_ic = hrow0 + (size_t)ic * 576;
        #pragma unroll 1
        for (int ky = 0; ky < 9; ++ky) {
            __syncthreads();
            // A stage: 128 oc x 16 k bf16, linear copy (coalesced uint4)
            const uint4* Ash = (const uint4*)(wBhi + wb_ic + (size_t)ky * 4096 + ocb * 2048);
            const uint4* Asl = (const uint4*)(wBlo + wb_ic + (size_t)ky * 4096 + ocb * 2048);
            ((uint4*)Ahi)[tid] = Ash[tid];
            ((uint4*)Alo)[tid] = Asl[tid];
            // B stage: per slot read 10 bf16 (kx window) from h row, pad to 16
            const unsigned int* hp =
                (const unsigned int*)(hsel + h_ic + (2 * oy + ky) * 24 + 2 * ox);
            unsigned int d0 = hp[0], d1 = hp[1], d2 = hp[2], d3 = hp[3], d4 = hp[4];
            unsigned short* Bdst = (role ? Blo : Bhi) + slot * 16;
            uint4 w0; w0.x = d0; w0.y = d1; w0.z = d2; w0.w = d3;
            uint4 w1; w1.x = d4 & 0xFFFFu; w1.y = 0u; w1.z = 0u; w1.w = 0u;
            *(uint4*)Bdst = w0;
            *(uint4*)(Bdst + 8) = w1;
            __syncthreads();
            // fragments
            bf16x8 ah[2], al[2], bh[2], bl[2];
            #pragma unroll
            for (int m = 0; m < 2; ++m) {
                const int rowoff = (wr * 64 + m * 32 + l31) * 16 + kh * 8;
                ah[m] = *(const bf16x8*)&Ahi[rowoff];
                al[m] = *(const bf16x8*)&Alo[rowoff];
            }
            #pragma unroll
            for (int n = 0; n < 2; ++n) {
                const int coloff = (wc * 64 + n * 32 + l31) * 16 + kh * 8;
                bh[n] = *(const bf16x8*)&Bhi[coloff];
                bl[n] = *(const bf16x8*)&Blo[coloff];
            }
            #pragma unroll
            for (int m = 0; m < 2; ++m)
                #pragma unroll
                for (int n = 0; n < 2; ++n) {
                    acc[m][n] = __builtin_amdgcn_mfma_f32_32x32x16_bf16(
                        ah[m], bh[n], acc[m][n], 0, 0, 0);
                    acc[m][n] = __builtin_amdgcn_mfma_f32_32x32x16_bf16(
                        ah[m], bl[n], acc[m][n], 0, 0, 0);
                    acc[m][n] = __builtin_amdgcn_mfma_f32_32x32x16_bf16(
                        al[m], bh[n], acc[m][n], 0, 0, 0);
                }
        }
    }
    // epilogue: D layout col=lane&31, row=(r&3)+8*(r>>2)+4*(lane>>5)
    #pragma unroll
    for (int m = 0; m < 2; ++m)
        #pragma unroll
        for (int n = 0; n < 2; ++n) {
            const int slotg = wc * 64 + n * 32 + l31;
            const int b = bpair * 2 + (slotg >> 6);
            const int pos = slotg & 63;
            #pragma unroll
            for (int r = 0; r < 16; ++r) {
                const int row = (r & 3) + 8 * (r >> 2) + 4 * kh;
                const int oc = ocb * 128 + wr * 64 + m * 32 + row;
                pp[(((size_t)ks * 64 + b) * 256 + oc) * 64 + pos] = acc[m][n][r];
            }
        }
}

// -------- reduce partials over ks, +bias, squash capsule rows of 8 -> u --------
__global__ __launch_bounds__(256) void reduce_bias_squash_kernel(
        const float* __restrict__ pp, const float* __restrict__ bias,
        float* __restrict__ u) {
    const int cap = blockIdx.x * 256 + threadIdx.x;   // 131072 capsules
    const int b = cap >> 11;
    const int rem = cap & 2047;
    const int oc = rem >> 3;
    const int oy = rem & 7;
    float4 sa = {0.f, 0.f, 0.f, 0.f}, sb = {0.f, 0.f, 0.f, 0.f};
    #pragma unroll
    for (int ks = 0; ks < 8; ++ks) {
        const float4* p4 = (const float4*)&pp[(((size_t)ks * 64 + b) * 256 + oc) * 64 + oy * 8];
        float4 a = p4[0], c = p4[1];
        sa.x += a.x; sa.y += a.y; sa.z += a.z; sa.w += a.w;
        sb.x += c.x; sb.y += c.y; sb.z += c.z; sb.w += c.w;
    }
    const float bv = bias[oc];
    sa.x += bv; sa.y += bv; sa.z += bv; sa.w += bv;
    sb.x += bv; sb.y += bv; sb.z += bv; sb.w += bv;
    float s2 = sa.x * sa.x + sa.y * sa.y + sa.z * sa.z + sa.w * sa.w
             + sb.x * sb.x + sb.y * sb.y + sb.z * sb.z + sb.w * sb.w;
    float scale = (s2 / (1.f + s2)) / sqrtf(s2 + 1e-8f);
    sa.x *= scale; sa.y *= scale; sa.z *= scale; sa.w *= scale;
    sb.x *= scale; sb.y *= scale; sb.z *= scale; sb.w *= scale;
    float4* up = (float4*)&u[(size_t)cap * 8];
    up[0] = sa;
    up[1] = sb;
}

// -------- weighted sum: s_part[o][st][b][d] = sum_i c[b,o,i]*u_hat[b,o,i,d] --------
template <int UNIFORM>
__global__ __launch_bounds__(256) void r_weighted_kernel(
        const float* __restrict__ W, const float* __restrict__ u,
        const float* __restrict__ cbuf, float* __restrict__ sp) {
    const int o = blockIdx.x;
    const int st = blockIdx.y;                 // 16 supertiles of 128 i
    __shared__ __align__(16) float Wl[16 * 128];   // [ii][d][k]
    __shared__ __align__(16) float ul[64 * 128];   // [b][ii][k]
    __shared__ float cl[64 * 16];                  // [b][ii]
    const int tid = threadIdx.x;
    const int d = tid & 15;
    const int bg = tid >> 4;
    float acc[4] = {0.f, 0.f, 0.f, 0.f};
    for (int sub = 0; sub < 8; ++sub) {
        const int i0 = st * 128 + sub * 16;
        __syncthreads();
        for (int idx = tid; idx < 2048; idx += 256)
            Wl[idx] = W[o * 262144 + i0 * 128 + idx];
        for (int idx = tid; idx < 8192; idx += 256) {
            int bb = idx >> 7, r = idx & 127;
            ul[idx] = u[bb * 16384 + i0 * 8 + r];
        }
        if (!UNIFORM) {
            for (int idx = tid; idx < 1024; idx += 256) {
                int bb = idx >> 4, ii = idx & 15;
                cl[idx] = cbuf[bb * (NO * NI) + o * NI + i0 + ii];
            }
        }
        __syncthreads();
        for (int ii = 0; ii < 16; ++ii) {
            const float4 wa = *(const float4*)&Wl[ii * 128 + d * 8];
            const float4 wb = *(const float4*)&Wl[ii * 128 + d * 8 + 4];
            #pragma unroll
            for (int j = 0; j < 4; ++j) {
                const int bb = bg + 16 * j;
                const float4 ua = *(const float4*)&ul[bb * 128 + ii * 8];
                const float4 ub = *(const float4*)&ul[bb * 128 + ii * 8 + 4];
                float uh = wa.x * ua.x + wa.y * ua.y + wa.z * ua.z + wa.w * ua.w
                         + wb.x * ub.x + wb.y * ub.y + wb.z * ub.z + wb.w * ub.w;
                float cv = UNIFORM ? 0.01f : cl[bb * 16 + ii];
                acc[j] = fmaf(cv, uh, acc[j]);
            }
        }
    }
    #pragma unroll
    for (int j = 0; j < 4; ++j) {
        const int bb = bg + 16 * j;
        sp[((o * 16 + st) * 64 + bb) * 16 + d] = acc[j];
    }
}

// -------- reduce partials over st, squash over d, write v (or final out) --------
__global__ __launch_bounds__(256) void squash_v_kernel(const float* __restrict__ sp,
        float* __restrict__ dest) {
    const int t = blockIdx.x * 256 + threadIdx.x;  // 102400 slots
    const int d = t & 15;
    const int cap = t >> 4;                        // o*64 + b
    const int o = cap >> 6;
    const int bb = cap & 63;
    float s = 0.f;
    #pragma unroll
    for (int st = 0; st < 16; ++st)
        s += sp[((o * 16 + st) * 64 + bb) * 16 + d];
    float s2 = s * s;
    #pragma unroll
    for (int off = 1; off < 16; off <<= 1)
        s2 += __shfl_xor(s2, off, 16);
    float scale = (s2 / (1.f + s2)) / sqrtf(s2 + 1e-8f);
    dest[(bb * NO + o) * ND + d] = s * scale;
}

// -------- logits: b[b,o,i] (+)= sum_d u_hat[b,o,i,d] * v[b,o,d] --------
template <int ADD>
__global__ __launch_bounds__(256) void r_logits_kernel(
        const float* __restrict__ W, const float* __restrict__ u,
        const float* __restrict__ v, float* __restrict__ bbuf) {
    const int o = blockIdx.x;
    const int st = blockIdx.y;
    __shared__ __align__(16) float Wl[16 * 128];
    __shared__ __align__(16) float ul[64 * 128];
    __shared__ float vl[64 * 16];
    const int tid = threadIdx.x;
    const int ii = tid & 15;
    const int bg = tid >> 4;
    for (int idx = tid; idx < 1024; idx += 256) {
        int bb = idx >> 4, dd = idx & 15;
        vl[idx] = v[(bb * NO + o) * ND + dd];
    }
    for (int sub = 0; sub < 8; ++sub) {
        const int i0 = st * 128 + sub * 16;
        __syncthreads();
        for (int idx = tid; idx < 2048; idx += 256)
            Wl[idx] = W[o * 262144 + i0 * 128 + idx];
        for (int idx = tid; idx < 8192; idx += 256) {
            int bb = idx >> 7, r = idx & 127;
            ul[idx] = u[bb * 16384 + i0 * 8 + r];
        }
        __syncthreads();
        float4 ua[4], ub[4];
        #pragma unroll
        for (int j = 0; j < 4; ++j) {
            const int bb = bg + 16 * j;
            ua[j] = *(const float4*)&ul[bb * 128 + ii * 8];
            ub[j] = *(const float4*)&ul[bb * 128 + ii * 8 + 4];
        }
        float tmp[4] = {0.f, 0.f, 0.f, 0.f};
        for (int dd = 0; dd < 16; ++dd) {
            const float4 wa = *(const float4*)&Wl[ii * 128 + dd * 8];
            const float4 wb = *(const float4*)&Wl[ii * 128 + dd * 8 + 4];
            #pragma unroll
            for (int j = 0; j < 4; ++j) {
                float uh = wa.x * ua[j].x + wa.y * ua[j].y + wa.z * ua[j].z + wa.w * ua[j].w
                         + wb.x * ub[j].x + wb.y * ub[j].y + wb.z * ub[j].z + wb.w * ub[j].w;
                tmp[j] = fmaf(uh, vl[(bg + 16 * j) * 16 + dd], tmp[j]);
            }
        }
        #pragma unroll
        for (int j = 0; j < 4; ++j) {
            const int bb = bg + 16 * j;
            const int addr = bb * (NO * NI) + o * NI + i0 + ii;
            bbuf[addr] = (ADD ? bbuf[addr] : 0.f) + tmp[j];
        }
    }
}

// -------- softmax over o (axis=1) of b -> c --------
__global__ __launch_bounds__(256) void softmax_kernel(const float* __restrict__ bbuf,
        float* __restrict__ cbuf) {
    const int bb = blockIdx.x >> 3;
    const int i = (blockIdx.x & 7) * 256 + threadIdx.x;
    const float* col = bbuf + bb * (NO * NI) + i;
    float m = -1e30f;
    for (int o = 0; o < NO; ++o) m = fmaxf(m, col[o * NI]);
    float s = 0.f;
    for (int o = 0; o < NO; ++o) s += __expf(col[o * NI] - m);
    const float inv = 1.f / s;
    float* outp = cbuf + bb * (NO * NI) + i;
    for (int o = 0; o < NO; ++o) outp[o * NI] = __expf(col[o * NI] - m) * inv;
}

extern "C" void kernel_launch(void* const* d_in, const int* in_sizes, int n_in,
                              void* d_out, int out_size, void* d_ws, size_t ws_size,
                              hipStream_t stream) {
    (void)in_sizes; (void)n_in; (void)out_size; (void)ws_size;
    const float* x      = (const float*)d_in[0];
    const float* conv_w = (const float*)d_in[1];
    const float* conv_b = (const float*)d_in[2];
    const float* pcap_w = (const float*)d_in[3];
    const float* pcap_b = (const float*)d_in[4];
    const float* W      = (const float*)d_in[5];
    float* out = (float*)d_out;
    float* ws  = (float*)d_ws;
    unsigned short* h_hi = (unsigned short*)(ws + WS_H);
    unsigned short* h_lo = h_hi + 9437184;
    unsigned short* wBhi = (unsigned short*)(ws + WS_CB);  // dead cbf slot pre-routing
    unsigned short* wBlo = wBhi + 9437184;
    float* u   = ws + WS_U;
    float* bbf = ws + WS_BB;
    float* cbf = ws + WS_CB;
    float* sp  = ws + WS_SP;
    float* v   = ws + WS_V;
    float* pp  = ws + WS_PP;   // overlaps bbf (dead until routing)

    wb_precompute_kernel<<<dim3(256, 4), 256, 0, stream>>>(pcap_w, wBhi, wBlo);
    conv1_kernel<<<dim3(64, 16), 256, 0, stream>>>(x, conv_w, conv_b, h_hi, h_lo);
    conv2_mfma_kernel<<<dim3(32, 2, 8), 256, 0, stream>>>(h_hi, h_lo, wBhi, wBlo, pp);
    reduce_bias_squash_kernel<<<512, 256, 0, stream>>>(pp, pcap_b, u);
    // routing iter 0 (c uniform = 1/100)
    r_weighted_kernel<1><<<dim3(100, 16), 256, 0, stream>>>(W, u, nullptr, sp);
    squash_v_kernel<<<400, 256, 0, stream>>>(sp, v);
    r_logits_kernel<0><<<dim3(100, 16), 256, 0, stream>>>(W, u, v, bbf);
    // routing iter 1
    softmax_kernel<<<512, 256, 0, stream>>>(bbf, cbf);
    r_weighted_kernel<0><<<dim3(100, 16), 256, 0, stream>>>(W, u, cbf, sp);
    squash_v_kernel<<<400, 256, 0, stream>>>(sp, v);
    r_logits_kernel<1><<<dim3(100, 16), 256, 0, stream>>>(W, u, v, bbf);
    // routing iter 2
    softmax_kernel<<<512, 256, 0, stream>>>(bbf, cbf);
    r_weighted_kernel<0><<<dim3(100, 16), 256, 0, stream>>>(W, u, cbf, sp);
    squash_v_kernel<<<400, 256, 0, stream>>>(sp, out);
}

// Round 10
// 1133.643 us; speedup vs baseline: 1.6679x; 1.3272x over previous
//
#include <hip/hip_runtime.h>

#define NB 64
#define NO 100
#define NI 2048
#define ND 16
#define NK 8

// ws layout (float offsets)
#define WS_H    0            // h_hi + h_lo: 2x 9437184 ushort = 9437184 floats
#define WS_U    9437184      // u: 64*2048*8 = 1048576
#define WS_BB   10485760     // b logits: 13107200 (pp overlaps here pre-routing)
#define WS_CB   23592960     // c: 13107200 (wB_hi/lo overlap here pre-routing)
#define WS_SP   36700160     // s partials: 100*8*64*16 = 819200 (region sized 1638400)
#define WS_V    38338560     // v: 102400
#define WS_PP   WS_BB        // conv2 partials: 8*64*256*64 = 8388608 floats

typedef __attribute__((ext_vector_type(8))) short bf16x8;
typedef __attribute__((ext_vector_type(16))) float f32x16;
typedef __attribute__((ext_vector_type(4))) float f32x4;

__device__ inline unsigned short f2bf(float x) {   // RNE float->bf16
    union { float f; unsigned u; } v; v.f = x;
    unsigned r = (v.u + 0x7FFFu + ((v.u >> 16) & 1u)) >> 16;
    return (unsigned short)r;
}
__device__ inline float bf2f(unsigned short h) {
    union { unsigned u; float f; } v; v.u = ((unsigned)h) << 16;
    return v.f;
}

// ---------------- conv1: [64,3,32,32] -> relu -> h_hi/h_lo bf16 [64,256,24,24] ----
__global__ __launch_bounds__(256) void conv1_kernel(const float* __restrict__ x,
        const float* __restrict__ w, const float* __restrict__ bias,
        unsigned short* __restrict__ h_hi, unsigned short* __restrict__ h_lo) {
    const int b = blockIdx.x;
    const int ocg = blockIdx.y;          // 16 oc per block
    __shared__ float xl[3 * 32 * 32];
    __shared__ float wl[16 * 243];
    const int tid = threadIdx.x;
    for (int idx = tid; idx < 3072; idx += 256) xl[idx] = x[b * 3072 + idx];
    for (int idx = tid; idx < 16 * 243; idx += 256)
        wl[idx] = w[ocg * 16 * 243 + idx];
    __syncthreads();
    const int lane = tid & 63;
    const int wg = tid >> 6;             // 0..3 -> 4 oc each
    float acc[4][9];
    #pragma unroll
    for (int jj = 0; jj < 4; ++jj) {
        float bv = bias[ocg * 16 + wg * 4 + jj];
        #pragma unroll
        for (int j = 0; j < 9; ++j) acc[jj][j] = bv;
    }
    int xbase[9];
    #pragma unroll
    for (int j = 0; j < 9; ++j) {
        int p = lane + 64 * j;           // 576 positions exactly
        xbase[j] = (p / 24) * 32 + (p % 24);
    }
    for (int ic = 0; ic < 3; ++ic)
        for (int ky = 0; ky < 9; ++ky) {
            #pragma unroll
            for (int kx = 0; kx < 9; ++kx) {
                float wv[4];
                #pragma unroll
                for (int jj = 0; jj < 4; ++jj)
                    wv[jj] = wl[(wg * 4 + jj) * 243 + ic * 81 + ky * 9 + kx];
                #pragma unroll
                for (int j = 0; j < 9; ++j) {
                    float xv = xl[ic * 1024 + xbase[j] + ky * 32 + kx];
                    #pragma unroll
                    for (int jj = 0; jj < 4; ++jj)
                        acc[jj][j] = fmaf(xv, wv[jj], acc[jj][j]);
                }
            }
        }
    #pragma unroll
    for (int jj = 0; jj < 4; ++jj) {
        int oc = ocg * 16 + wg * 4 + jj;
        #pragma unroll
        for (int j = 0; j < 9; ++j) {
            int p = lane + 64 * j;
            float v = fmaxf(acc[jj][j], 0.f);
            unsigned short hi = f2bf(v);
            unsigned short lo = f2bf(v - bf2f(hi));
            size_t o = (size_t)(b * 256 + oc) * 576 + p;
            h_hi[o] = hi;
            h_lo[o] = lo;
        }
    }
}

// ---- precompute wB_hi/lo[ic][ky][oc][16] bf16 (kx 0..8, pad 9..15 = 0) ----
__global__ __launch_bounds__(256) void wb_precompute_kernel(const float* __restrict__ w,
        unsigned short* __restrict__ wBhi, unsigned short* __restrict__ wBlo) {
    const int ic = blockIdx.x;           // 0..255
    const int ocq = blockIdx.y;          // 0..3 (64 oc each)
    __shared__ float tl[64][85];
    const int tid = threadIdx.x;
    for (int f = tid; f < 5184; f += 256) {
        int oc = f / 81, kk = f % 81;
        tl[oc][kk] = w[(size_t)(ocq * 64 + oc) * 20736 + ic * 81 + kk];
    }
    __syncthreads();
    for (int idx = tid; idx < 9216; idx += 256) {   // 9 ky * 64 oc * 16 kx
        int ky = idx >> 10;
        int rem = idx & 1023;
        int ocl = rem >> 4;
        int kx = rem & 15;
        float val = (kx < 9) ? tl[ocl][ky * 9 + kx] : 0.f;
        unsigned short hi = f2bf(val);
        unsigned short lo = f2bf(val - bf2f(hi));
        size_t dst = ((size_t)(ic * 9 + ky) * 256 + ocq * 64 + ocl) * 16 + kx;
        wBhi[dst] = hi;
        wBlo[dst] = lo;
    }
}

// ---------------- conv2 via MFMA (split-bf16): partials over ks ----------------
__global__ __launch_bounds__(256) void conv2_mfma_kernel(
        const unsigned short* __restrict__ h_hi, const unsigned short* __restrict__ h_lo,
        const unsigned short* __restrict__ wBhi, const unsigned short* __restrict__ wBlo,
        float* __restrict__ pp) {
    const int bpair = blockIdx.x;        // 0..31
    const int ocb = blockIdx.y;          // 0..1  (128 oc)
    const int ks = blockIdx.z;           // 0..7  (32 ic)
    __shared__ __align__(16) unsigned short Ahi[128 * 16];
    __shared__ __align__(16) unsigned short Alo[128 * 16];
    __shared__ __align__(16) unsigned short Bhi[128 * 16];
    __shared__ __align__(16) unsigned short Blo[128 * 16];
    const int tid = threadIdx.x;
    const int lane = tid & 63;
    const int wid = tid >> 6;
    const int wr = wid >> 1, wc = wid & 1;        // wave tile origin (64x64)
    const int l31 = lane & 31, kh = lane >> 5;
    const int slot = tid & 127;                    // blocal*64 + oy*8 + ox
    const int role = tid >> 7;                     // 0: hi, 1: lo
    const int oy = (slot >> 3) & 7;
    const int ox = slot & 7;
    const unsigned short* hsel = role ? h_lo : h_hi;
    const size_t hrow0 = ((size_t)(bpair * 2 + (slot >> 6)) * 256) * 576;

    f32x16 acc[2][2];
    #pragma unroll
    for (int m = 0; m < 2; ++m)
        #pragma unroll
        for (int n = 0; n < 2; ++n)
            #pragma unroll
            for (int r = 0; r < 16; ++r) acc[m][n][r] = 0.f;

    const int ic0 = ks * 32;
    for (int ic = ic0; ic < ic0 + 32; ++ic) {
        const size_t wb_ic = (size_t)ic * 9 * 4096;      // *256*16
        const size_t h_ic = hrow0 + (size_t)ic * 576;
        #pragma unroll 1
        for (int ky = 0; ky < 9; ++ky) {
            __syncthreads();
            const uint4* Ash = (const uint4*)(wBhi + wb_ic + (size_t)ky * 4096 + ocb * 2048);
            const uint4* Asl = (const uint4*)(wBlo + wb_ic + (size_t)ky * 4096 + ocb * 2048);
            ((uint4*)Ahi)[tid] = Ash[tid];
            ((uint4*)Alo)[tid] = Asl[tid];
            const unsigned int* hp =
                (const unsigned int*)(hsel + h_ic + (2 * oy + ky) * 24 + 2 * ox);
            unsigned int d0 = hp[0], d1 = hp[1], d2 = hp[2], d3 = hp[3], d4 = hp[4];
            unsigned short* Bdst = (role ? Blo : Bhi) + slot * 16;
            uint4 w0; w0.x = d0; w0.y = d1; w0.z = d2; w0.w = d3;
            uint4 w1; w1.x = d4 & 0xFFFFu; w1.y = 0u; w1.z = 0u; w1.w = 0u;
            *(uint4*)Bdst = w0;
            *(uint4*)(Bdst + 8) = w1;
            __syncthreads();
            bf16x8 ah[2], al[2], bh[2], bl[2];
            #pragma unroll
            for (int m = 0; m < 2; ++m) {
                const int rowoff = (wr * 64 + m * 32 + l31) * 16 + kh * 8;
                ah[m] = *(const bf16x8*)&Ahi[rowoff];
                al[m] = *(const bf16x8*)&Alo[rowoff];
            }
            #pragma unroll
            for (int n = 0; n < 2; ++n) {
                const int coloff = (wc * 64 + n * 32 + l31) * 16 + kh * 8;
                bh[n] = *(const bf16x8*)&Bhi[coloff];
                bl[n] = *(const bf16x8*)&Blo[coloff];
            }
            #pragma unroll
            for (int m = 0; m < 2; ++m)
                #pragma unroll
                for (int n = 0; n < 2; ++n) {
                    acc[m][n] = __builtin_amdgcn_mfma_f32_32x32x16_bf16(
                        ah[m], bh[n], acc[m][n], 0, 0, 0);
                    acc[m][n] = __builtin_amdgcn_mfma_f32_32x32x16_bf16(
                        ah[m], bl[n], acc[m][n], 0, 0, 0);
                    acc[m][n] = __builtin_amdgcn_mfma_f32_32x32x16_bf16(
                        al[m], bh[n], acc[m][n], 0, 0, 0);
                }
        }
    }
    #pragma unroll
    for (int m = 0; m < 2; ++m)
        #pragma unroll
        for (int n = 0; n < 2; ++n) {
            const int slotg = wc * 64 + n * 32 + l31;
            const int b = bpair * 2 + (slotg >> 6);
            const int pos = slotg & 63;
            #pragma unroll
            for (int r = 0; r < 16; ++r) {
                const int row = (r & 3) + 8 * (r >> 2) + 4 * kh;
                const int oc = ocb * 128 + wr * 64 + m * 32 + row;
                pp[(((size_t)ks * 64 + b) * 256 + oc) * 64 + pos] = acc[m][n][r];
            }
        }
}

// -------- reduce partials over ks, +bias, squash capsule rows of 8 -> u --------
__global__ __launch_bounds__(256) void reduce_bias_squash_kernel(
        const float* __restrict__ pp, const float* __restrict__ bias,
        float* __restrict__ u) {
    const int cap = blockIdx.x * 256 + threadIdx.x;   // 131072 capsules
    const int b = cap >> 11;
    const int rem = cap & 2047;
    const int oc = rem >> 3;
    const int oy = rem & 7;
    float4 sa = {0.f, 0.f, 0.f, 0.f}, sb = {0.f, 0.f, 0.f, 0.f};
    #pragma unroll
    for (int ks = 0; ks < 8; ++ks) {
        const float4* p4 = (const float4*)&pp[(((size_t)ks * 64 + b) * 256 + oc) * 64 + oy * 8];
        float4 a = p4[0], c = p4[1];
        sa.x += a.x; sa.y += a.y; sa.z += a.z; sa.w += a.w;
        sb.x += c.x; sb.y += c.y; sb.z += c.z; sb.w += c.w;
    }
    const float bv = bias[oc];
    sa.x += bv; sa.y += bv; sa.z += bv; sa.w += bv;
    sb.x += bv; sb.y += bv; sb.z += bv; sb.w += bv;
    float s2 = sa.x * sa.x + sa.y * sa.y + sa.z * sa.z + sa.w * sa.w
             + sb.x * sb.x + sb.y * sb.y + sb.z * sb.z + sb.w * sb.w;
    float scale = (s2 / (1.f + s2)) / sqrtf(s2 + 1e-8f);
    sa.x *= scale; sa.y *= scale; sa.z *= scale; sa.w *= scale;
    sb.x *= scale; sb.y *= scale; sb.z *= scale; sb.w *= scale;
    float4* up = (float4*)&u[(size_t)cap * 8];
    up[0] = sa;
    up[1] = sb;
}

// ---- r_weighted via MFMA: per-o GEMM C[16d x 64b] = W[o]^T · (c ⊙ u) ----
// K = (i,k) pairs; block (o, st) reduces i in [st*256, st*256+256).
// A[d][col] = W[o, i, d, k], B[b][col] = c[b,o,i]*u[b,i,k], col = i_l*8+k.
// Split-bf16: 3 MFMAs (hh, hl, lh) per K-chunk of 32. Rows padded to 72 bf16.
template <int UNIFORM>
__global__ __launch_bounds__(256) void r_weighted_mfma_kernel(
        const float* __restrict__ W, const float* __restrict__ u,
        const float* __restrict__ cbuf, float* __restrict__ sp) {
    const int o = blockIdx.x;
    const int st = blockIdx.y;              // 0..7 (256 i each)
    __shared__ __align__(16) unsigned short Ahi[16 * 72];
    __shared__ __align__(16) unsigned short Alo[16 * 72];
    __shared__ __align__(16) unsigned short Bhi[64 * 72];
    __shared__ __align__(16) unsigned short Blo[64 * 72];
    const int tid = threadIdx.x;
    const int lane = tid & 63;
    const int w = tid >> 6;                 // wave -> b tile [w*16, w*16+16)
    const int l15 = lane & 15;
    const int hi = lane >> 4;               // 0..3
    const int sb = tid >> 2;                // B staging: b 0..63
    const int si = tid & 3;                 // B staging: i_l base
    f32x4 acc = {0.f, 0.f, 0.f, 0.f};
    const float* Wo = W + (size_t)o * 262144;
    const int i_base = st * 256;
    #pragma unroll 1
    for (int iter = 0; iter < 32; ++iter) {
        const int i0 = i_base + iter * 8;
        __syncthreads();
        // A stage: 1024 contiguous floats = W[o, i0..i0+8, :, :]
        {
            float4 wv = *(const float4*)(Wo + (size_t)i0 * 128 + 4 * tid);
            const int i_l = tid >> 5;               // (4t)>>7
            const int d = (tid >> 1) & 15;
            const int k0 = (tid & 1) * 4;
            unsigned short* dh = Ahi + d * 72 + i_l * 8 + k0;
            unsigned short* dl = Alo + d * 72 + i_l * 8 + k0;
            float vv[4] = {wv.x, wv.y, wv.z, wv.w};
            unsigned int h01, h23, l01, l23;
            unsigned short h, l;
            h = f2bf(vv[0]); l = f2bf(vv[0] - bf2f(h)); h01 = h; l01 = l;
            h = f2bf(vv[1]); l = f2bf(vv[1] - bf2f(h)); h01 |= (unsigned)h << 16; l01 |= (unsigned)l << 16;
            h = f2bf(vv[2]); l = f2bf(vv[2] - bf2f(h)); h23 = h; l23 = l;
            h = f2bf(vv[3]); l = f2bf(vv[3] - bf2f(h)); h23 |= (unsigned)h << 16; l23 |= (unsigned)l << 16;
            *(unsigned int*)dh = h01; *(unsigned int*)(dh + 2) = h23;
            *(unsigned int*)dl = l01; *(unsigned int*)(dl + 2) = l23;
        }
        // B stage: cu for 8 i x 64 b (each thread: 2 (b,i) cells of 8 k)
        #pragma unroll
        for (int half = 0; half < 2; ++half) {
            const int i_l = si + 4 * half;
            const float* up = u + (size_t)sb * 16384 + (size_t)(i0 + i_l) * 8;
            float4 u0 = *(const float4*)up;
            float4 u1 = *(const float4*)(up + 4);
            float cv = UNIFORM ? 0.01f
                               : cbuf[(size_t)sb * (NO * NI) + o * NI + i0 + i_l];
            float q[8] = {u0.x * cv, u0.y * cv, u0.z * cv, u0.w * cv,
                          u1.x * cv, u1.y * cv, u1.z * cv, u1.w * cv};
            uint4 ph, pl;
            unsigned short h0, h1, l0, l1;
            h0 = f2bf(q[0]); l0 = f2bf(q[0] - bf2f(h0));
            h1 = f2bf(q[1]); l1 = f2bf(q[1] - bf2f(h1));
            ph.x = h0 | ((unsigned)h1 << 16); pl.x = l0 | ((unsigned)l1 << 16);
            h0 = f2bf(q[2]); l0 = f2bf(q[2] - bf2f(h0));
            h1 = f2bf(q[3]); l1 = f2bf(q[3] - bf2f(h1));
            ph.y = h0 | ((unsigned)h1 << 16); pl.y = l0 | ((unsigned)l1 << 16);
            h0 = f2bf(q[4]); l0 = f2bf(q[4] - bf2f(h0));
            h1 = f2bf(q[5]); l1 = f2bf(q[5] - bf2f(h1));
            ph.z = h0 | ((unsigned)h1 << 16); pl.z = l0 | ((unsigned)l1 << 16);
            h0 = f2bf(q[6]); l0 = f2bf(q[6] - bf2f(h0));
            h1 = f2bf(q[7]); l1 = f2bf(q[7] - bf2f(h1));
            ph.w = h0 | ((unsigned)h1 << 16); pl.w = l0 | ((unsigned)l1 << 16);
            *(uint4*)(Bhi + sb * 72 + i_l * 8) = ph;
            *(uint4*)(Blo + sb * 72 + i_l * 8) = pl;
        }
        __syncthreads();
        #pragma unroll
        for (int ch = 0; ch < 2; ++ch) {
            bf16x8 ah = *(const bf16x8*)(Ahi + l15 * 72 + ch * 32 + hi * 8);
            bf16x8 al = *(const bf16x8*)(Alo + l15 * 72 + ch * 32 + hi * 8);
            bf16x8 bh = *(const bf16x8*)(Bhi + (w * 16 + l15) * 72 + ch * 32 + hi * 8);
            bf16x8 bl = *(const bf16x8*)(Blo + (w * 16 + l15) * 72 + ch * 32 + hi * 8);
            acc = __builtin_amdgcn_mfma_f32_16x16x32_bf16(ah, bh, acc, 0, 0, 0);
            acc = __builtin_amdgcn_mfma_f32_16x16x32_bf16(ah, bl, acc, 0, 0, 0);
            acc = __builtin_amdgcn_mfma_f32_16x16x32_bf16(al, bh, acc, 0, 0, 0);
        }
    }
    // D: col = l15 -> b_local, row = hi*4 + reg -> d
    const int bg = w * 16 + l15;
    float4 st4;
    st4.x = acc[0]; st4.y = acc[1]; st4.z = acc[2]; st4.w = acc[3];
    *(float4*)&sp[(((size_t)o * 8 + st) * 64 + bg) * 16 + hi * 4] = st4;
}

// -------- reduce partials over st (8), squash over d, write v/out --------
__global__ __launch_bounds__(256) void squash_v_kernel(const float* __restrict__ sp,
        float* __restrict__ dest) {
    const int t = blockIdx.x * 256 + threadIdx.x;  // 102400 slots
    const int d = t & 15;
    const int cap = t >> 4;                        // o*64 + b
    const int o = cap >> 6;
    const int bb = cap & 63;
    float s = 0.f;
    #pragma unroll
    for (int st = 0; st < 8; ++st)
        s += sp[(((size_t)o * 8 + st) * 64 + bb) * 16 + d];
    float s2 = s * s;
    #pragma unroll
    for (int off = 1; off < 16; off <<= 1)
        s2 += __shfl_xor(s2, off, 16);
    float scale = (s2 / (1.f + s2)) / sqrtf(s2 + 1e-8f);
    dest[(bb * NO + o) * ND + d] = s * scale;
}

// -------- logits: b[b,o,i] (+)= sum_d u_hat[b,o,i,d] * v[b,o,d] --------
template <int ADD>
__global__ __launch_bounds__(256) void r_logits_kernel(
        const float* __restrict__ W, const float* __restrict__ u,
        const float* __restrict__ v, float* __restrict__ bbuf) {
    const int o = blockIdx.x;
    const int st = blockIdx.y;
    __shared__ __align__(16) float Wl[16 * 128];
    __shared__ __align__(16) float ul[64 * 128];
    __shared__ float vl[64 * 16];
    const int tid = threadIdx.x;
    const int ii = tid & 15;
    const int bg = tid >> 4;
    for (int idx = tid; idx < 1024; idx += 256) {
        int bb = idx >> 4, dd = idx & 15;
        vl[idx] = v[(bb * NO + o) * ND + dd];
    }
    for (int sub = 0; sub < 8; ++sub) {
        const int i0 = st * 128 + sub * 16;
        __syncthreads();
        for (int idx = tid; idx < 2048; idx += 256)
            Wl[idx] = W[o * 262144 + i0 * 128 + idx];
        for (int idx = tid; idx < 8192; idx += 256) {
            int bb = idx >> 7, r = idx & 127;
            ul[idx] = u[bb * 16384 + i0 * 8 + r];
        }
        __syncthreads();
        float4 ua[4], ub[4];
        #pragma unroll
        for (int j = 0; j < 4; ++j) {
            const int bb = bg + 16 * j;
            ua[j] = *(const float4*)&ul[bb * 128 + ii * 8];
            ub[j] = *(const float4*)&ul[bb * 128 + ii * 8 + 4];
        }
        float tmp[4] = {0.f, 0.f, 0.f, 0.f};
        for (int dd = 0; dd < 16; ++dd) {
            const float4 wa = *(const float4*)&Wl[ii * 128 + dd * 8];
            const float4 wb = *(const float4*)&Wl[ii * 128 + dd * 8 + 4];
            #pragma unroll
            for (int j = 0; j < 4; ++j) {
                float uh = wa.x * ua[j].x + wa.y * ua[j].y + wa.z * ua[j].z + wa.w * ua[j].w
                         + wb.x * ub[j].x + wb.y * ub[j].y + wb.z * ub[j].z + wb.w * ub[j].w;
                tmp[j] = fmaf(uh, vl[(bg + 16 * j) * 16 + dd], tmp[j]);
            }
        }
        #pragma unroll
        for (int j = 0; j < 4; ++j) {
            const int bb = bg + 16 * j;
            const int addr = bb * (NO * NI) + o * NI + i0 + ii;
            bbuf[addr] = (ADD ? bbuf[addr] : 0.f) + tmp[j];
        }
    }
}

// -------- softmax over o (axis=1) of b -> c --------
__global__ __launch_bounds__(256) void softmax_kernel(const float* __restrict__ bbuf,
        float* __restrict__ cbuf) {
    const int bb = blockIdx.x >> 3;
    const int i = (blockIdx.x & 7) * 256 + threadIdx.x;
    const float* col = bbuf + bb * (NO * NI) + i;
    float m = -1e30f;
    for (int o = 0; o < NO; ++o) m = fmaxf(m, col[o * NI]);
    float s = 0.f;
    for (int o = 0; o < NO; ++o) s += __expf(col[o * NI] - m);
    const float inv = 1.f / s;
    float* outp = cbuf + bb * (NO * NI) + i;
    for (int o = 0; o < NO; ++o) outp[o * NI] = __expf(col[o * NI] - m) * inv;
}

extern "C" void kernel_launch(void* const* d_in, const int* in_sizes, int n_in,
                              void* d_out, int out_size, void* d_ws, size_t ws_size,
                              hipStream_t stream) {
    (void)in_sizes; (void)n_in; (void)out_size; (void)ws_size;
    const float* x      = (const float*)d_in[0];
    const float* conv_w = (const float*)d_in[1];
    const float* conv_b = (const float*)d_in[2];
    const float* pcap_w = (const float*)d_in[3];
    const float* pcap_b = (const float*)d_in[4];
    const float* W      = (const float*)d_in[5];
    float* out = (float*)d_out;
    float* ws  = (float*)d_ws;
    unsigned short* h_hi = (unsigned short*)(ws + WS_H);
    unsigned short* h_lo = h_hi + 9437184;
    unsigned short* wBhi = (unsigned short*)(ws + WS_CB);  // dead cbf slot pre-routing
    unsigned short* wBlo = wBhi + 9437184;
    float* u   = ws + WS_U;
    float* bbf = ws + WS_BB;
    float* cbf = ws + WS_CB;
    float* sp  = ws + WS_SP;
    float* v   = ws + WS_V;
    float* pp  = ws + WS_PP;   // overlaps bbf (dead until routing)

    wb_precompute_kernel<<<dim3(256, 4), 256, 0, stream>>>(pcap_w, wBhi, wBlo);
    conv1_kernel<<<dim3(64, 16), 256, 0, stream>>>(x, conv_w, conv_b, h_hi, h_lo);
    conv2_mfma_kernel<<<dim3(32, 2, 8), 256, 0, stream>>>(h_hi, h_lo, wBhi, wBlo, pp);
    reduce_bias_squash_kernel<<<512, 256, 0, stream>>>(pp, pcap_b, u);
    // routing iter 0 (c uniform = 1/100)
    r_weighted_mfma_kernel<1><<<dim3(100, 8), 256, 0, stream>>>(W, u, nullptr, sp);
    squash_v_kernel<<<400, 256, 0, stream>>>(sp, v);
    r_logits_kernel<0><<<dim3(100, 16), 256, 0, stream>>>(W, u, v, bbf);
    // routing iter 1
    softmax_kernel<<<512, 256, 0, stream>>>(bbf, cbf);
    r_weighted_mfma_kernel<0><<<dim3(100, 8), 256, 0, stream>>>(W, u, cbf, sp);
    squash_v_kernel<<<400, 256, 0, stream>>>(sp, v);
    r_logits_kernel<1><<<dim3(100, 16), 256, 0, stream>>>(W, u, v, bbf);
    // routing iter 2
    softmax_kernel<<<512, 256, 0, stream>>>(bbf, cbf);
    r_weighted_mfma_kernel<0><<<dim3(100, 8), 256, 0, stream>>>(W, u, cbf, sp);
    squash_v_kernel<<<400, 256, 0, stream>>>(sp, out);
}

// Round 12
// 832.559 us; speedup vs baseline: 2.2710x; 1.3616x over previous
//
#include <hip/hip_runtime.h>

#define NB 64
#define NO 100
#define NI 2048
#define ND 16
#define NK 8

// ws layout (float offsets)
#define WS_H    0            // h_hi/h_lo (conv phase); ut [16384][64] (routing phase)
#define WS_U    9437184      // u: 64*2048*8 = 1048576
#define WS_BB   10485760     // b logits: 13107200 (pp overlaps here pre-routing)
#define WS_CB   23592960     // c: 13107200 (wB_hi/lo overlap here pre-routing)
#define WS_SP   36700160     // s partials: 100*8*64*16 = 819200
#define WS_V    38338560     // v: 102400
#define WS_PP   WS_BB        // conv2 partials: 8*64*256*64 = 8388608 floats

typedef __attribute__((ext_vector_type(8))) short bf16x8;
typedef __attribute__((ext_vector_type(16))) float f32x16;
typedef __attribute__((ext_vector_type(4))) float f32x4;

__device__ inline unsigned short f2bf(float x) {   // RNE float->bf16
    union { float f; unsigned u; } v; v.f = x;
    unsigned r = (v.u + 0x7FFFu + ((v.u >> 16) & 1u)) >> 16;
    return (unsigned short)r;
}
__device__ inline float bf2f(unsigned short h) {
    union { unsigned u; float f; } v; v.u = ((unsigned)h) << 16;
    return v.f;
}

// ---------------- conv1: [64,3,32,32] -> relu -> h_hi/h_lo bf16 ----------------
__global__ __launch_bounds__(256) void conv1_kernel(const float* __restrict__ x,
        const float* __restrict__ w, const float* __restrict__ bias,
        unsigned short* __restrict__ h_hi, unsigned short* __restrict__ h_lo) {
    const int b = blockIdx.x;
    const int ocg = blockIdx.y;
    __shared__ float xl[3 * 32 * 32];
    __shared__ float wl[16 * 243];
    const int tid = threadIdx.x;
    for (int idx = tid; idx < 3072; idx += 256) xl[idx] = x[b * 3072 + idx];
    for (int idx = tid; idx < 16 * 243; idx += 256)
        wl[idx] = w[ocg * 16 * 243 + idx];
    __syncthreads();
    const int lane = tid & 63;
    const int wg = tid >> 6;
    float acc[4][9];
    #pragma unroll
    for (int jj = 0; jj < 4; ++jj) {
        float bv = bias[ocg * 16 + wg * 4 + jj];
        #pragma unroll
        for (int j = 0; j < 9; ++j) acc[jj][j] = bv;
    }
    int xbase[9];
    #pragma unroll
    for (int j = 0; j < 9; ++j) {
        int p = lane + 64 * j;
        xbase[j] = (p / 24) * 32 + (p % 24);
    }
    for (int ic = 0; ic < 3; ++ic)
        for (int ky = 0; ky < 9; ++ky) {
            #pragma unroll
            for (int kx = 0; kx < 9; ++kx) {
                float wv[4];
                #pragma unroll
                for (int jj = 0; jj < 4; ++jj)
                    wv[jj] = wl[(wg * 4 + jj) * 243 + ic * 81 + ky * 9 + kx];
                #pragma unroll
                for (int j = 0; j < 9; ++j) {
                    float xv = xl[ic * 1024 + xbase[j] + ky * 32 + kx];
                    #pragma unroll
                    for (int jj = 0; jj < 4; ++jj)
                        acc[jj][j] = fmaf(xv, wv[jj], acc[jj][j]);
                }
            }
        }
    #pragma unroll
    for (int jj = 0; jj < 4; ++jj) {
        int oc = ocg * 16 + wg * 4 + jj;
        #pragma unroll
        for (int j = 0; j < 9; ++j) {
            int p = lane + 64 * j;
            float v = fmaxf(acc[jj][j], 0.f);
            unsigned short hi = f2bf(v);
            unsigned short lo = f2bf(v - bf2f(hi));
            size_t o = (size_t)(b * 256 + oc) * 576 + p;
            h_hi[o] = hi;
            h_lo[o] = lo;
        }
    }
}

// ---- precompute wB_hi/lo[ic][ky][oc][16] bf16 (kx 0..8, pad 9..15 = 0) ----
__global__ __launch_bounds__(256) void wb_precompute_kernel(const float* __restrict__ w,
        unsigned short* __restrict__ wBhi, unsigned short* __restrict__ wBlo) {
    const int ic = blockIdx.x;
    const int ocq = blockIdx.y;
    __shared__ float tl[64][85];
    const int tid = threadIdx.x;
    for (int f = tid; f < 5184; f += 256) {
        int oc = f / 81, kk = f % 81;
        tl[oc][kk] = w[(size_t)(ocq * 64 + oc) * 20736 + ic * 81 + kk];
    }
    __syncthreads();
    for (int idx = tid; idx < 9216; idx += 256) {
        int ky = idx >> 10;
        int rem = idx & 1023;
        int ocl = rem >> 4;
        int kx = rem & 15;
        float val = (kx < 9) ? tl[ocl][ky * 9 + kx] : 0.f;
        unsigned short hi = f2bf(val);
        unsigned short lo = f2bf(val - bf2f(hi));
        size_t dst = ((size_t)(ic * 9 + ky) * 256 + ocq * 64 + ocl) * 16 + kx;
        wBhi[dst] = hi;
        wBlo[dst] = lo;
    }
}

// ---------------- conv2 via MFMA (split-bf16): partials over ks ----------------
__global__ __launch_bounds__(256) void conv2_mfma_kernel(
        const unsigned short* __restrict__ h_hi, const unsigned short* __restrict__ h_lo,
        const unsigned short* __restrict__ wBhi, const unsigned short* __restrict__ wBlo,
        float* __restrict__ pp) {
    const int bpair = blockIdx.x;
    const int ocb = blockIdx.y;
    const int ks = blockIdx.z;
    __shared__ __align__(16) unsigned short Ahi[128 * 16];
    __shared__ __align__(16) unsigned short Alo[128 * 16];
    __shared__ __align__(16) unsigned short Bhi[128 * 16];
    __shared__ __align__(16) unsigned short Blo[128 * 16];
    const int tid = threadIdx.x;
    const int lane = tid & 63;
    const int wid = tid >> 6;
    const int wr = wid >> 1, wc = wid & 1;
    const int l31 = lane & 31, kh = lane >> 5;
    const int slot = tid & 127;
    const int role = tid >> 7;
    const int oy = (slot >> 3) & 7;
    const int ox = slot & 7;
    const unsigned short* hsel = role ? h_lo : h_hi;
    const size_t hrow0 = ((size_t)(bpair * 2 + (slot >> 6)) * 256) * 576;

    f32x16 acc[2][2];
    #pragma unroll
    for (int m = 0; m < 2; ++m)
        #pragma unroll
        for (int n = 0; n < 2; ++n)
            #pragma unroll
            for (int r = 0; r < 16; ++r) acc[m][n][r] = 0.f;

    const int ic0 = ks * 32;
    for (int ic = ic0; ic < ic0 + 32; ++ic) {
        const size_t wb_ic = (size_t)ic * 9 * 4096;
        const size_t h_ic = hrow0 + (size_t)ic * 576;
        #pragma unroll 1
        for (int ky = 0; ky < 9; ++ky) {
            __syncthreads();
            const uint4* Ash = (const uint4*)(wBhi + wb_ic + (size_t)ky * 4096 + ocb * 2048);
            const uint4* Asl = (const uint4*)(wBlo + wb_ic + (size_t)ky * 4096 + ocb * 2048);
            ((uint4*)Ahi)[tid] = Ash[tid];
            ((uint4*)Alo)[tid] = Asl[tid];
            const unsigned int* hp =
                (const unsigned int*)(hsel + h_ic + (2 * oy + ky) * 24 + 2 * ox);
            unsigned int d0 = hp[0], d1 = hp[1], d2 = hp[2], d3 = hp[3], d4 = hp[4];
            unsigned short* Bdst = (role ? Blo : Bhi) + slot * 16;
            uint4 w0; w0.x = d0; w0.y = d1; w0.z = d2; w0.w = d3;
            uint4 w1; w1.x = d4 & 0xFFFFu; w1.y = 0u; w1.z = 0u; w1.w = 0u;
            *(uint4*)Bdst = w0;
            *(uint4*)(Bdst + 8) = w1;
            __syncthreads();
            bf16x8 ah[2], al[2], bh[2], bl[2];
            #pragma unroll
            for (int m = 0; m < 2; ++m) {
                const int rowoff = (wr * 64 + m * 32 + l31) * 16 + kh * 8;
                ah[m] = *(const bf16x8*)&Ahi[rowoff];
                al[m] = *(const bf16x8*)&Alo[rowoff];
            }
            #pragma unroll
            for (int n = 0; n < 2; ++n) {
                const int coloff = (wc * 64 + n * 32 + l31) * 16 + kh * 8;
                bh[n] = *(const bf16x8*)&Bhi[coloff];
                bl[n] = *(const bf16x8*)&Blo[coloff];
            }
            #pragma unroll
            for (int m = 0; m < 2; ++m)
                #pragma unroll
                for (int n = 0; n < 2; ++n) {
                    acc[m][n] = __builtin_amdgcn_mfma_f32_32x32x16_bf16(
                        ah[m], bh[n], acc[m][n], 0, 0, 0);
                    acc[m][n] = __builtin_amdgcn_mfma_f32_32x32x16_bf16(
                        ah[m], bl[n], acc[m][n], 0, 0, 0);
                    acc[m][n] = __builtin_amdgcn_mfma_f32_32x32x16_bf16(
                        al[m], bh[n], acc[m][n], 0, 0, 0);
                }
        }
    }
    #pragma unroll
    for (int m = 0; m < 2; ++m)
        #pragma unroll
        for (int n = 0; n < 2; ++n) {
            const int slotg = wc * 64 + n * 32 + l31;
            const int b = bpair * 2 + (slotg >> 6);
            const int pos = slotg & 63;
            #pragma unroll
            for (int r = 0; r < 16; ++r) {
                const int row = (r & 3) + 8 * (r >> 2) + 4 * kh;
                const int oc = ocb * 128 + wr * 64 + m * 32 + row;
                pp[(((size_t)ks * 64 + b) * 256 + oc) * 64 + pos] = acc[m][n][r];
            }
        }
}

// -------- reduce partials over ks, +bias, squash capsule rows of 8 -> u --------
__global__ __launch_bounds__(256) void reduce_bias_squash_kernel(
        const float* __restrict__ pp, const float* __restrict__ bias,
        float* __restrict__ u) {
    const int cap = blockIdx.x * 256 + threadIdx.x;
    const int b = cap >> 11;
    const int rem = cap & 2047;
    const int oc = rem >> 3;
    const int oy = rem & 7;
    float4 sa = {0.f, 0.f, 0.f, 0.f}, sb = {0.f, 0.f, 0.f, 0.f};
    #pragma unroll
    for (int ks = 0; ks < 8; ++ks) {
        const float4* p4 = (const float4*)&pp[(((size_t)ks * 64 + b) * 256 + oc) * 64 + oy * 8];
        float4 a = p4[0], c = p4[1];
        sa.x += a.x; sa.y += a.y; sa.z += a.z; sa.w += a.w;
        sb.x += c.x; sb.y += c.y; sb.z += c.z; sb.w += c.w;
    }
    const float bv = bias[oc];
    sa.x += bv; sa.y += bv; sa.z += bv; sa.w += bv;
    sb.x += bv; sb.y += bv; sb.z += bv; sb.w += bv;
    float s2 = sa.x * sa.x + sa.y * sa.y + sa.z * sa.z + sa.w * sa.w
             + sb.x * sb.x + sb.y * sb.y + sb.z * sb.z + sb.w * sb.w;
    float scale = (s2 / (1.f + s2)) / sqrtf(s2 + 1e-8f);
    sa.x *= scale; sa.y *= scale; sa.z *= scale; sa.w *= scale;
    sb.x *= scale; sb.y *= scale; sb.z *= scale; sb.w *= scale;
    float4* up = (float4*)&u[(size_t)cap * 8];
    up[0] = sa;
    up[1] = sb;
}

// -------- transpose u -> ut[(i*8+k)][b] (once per launch; u fixed in routing) ----
__global__ __launch_bounds__(256) void transpose_u_kernel(const float* __restrict__ u,
        float* __restrict__ ut) {
    const int blk = blockIdx.x;          // 128 blocks x 128 (i,k)-rows
    __shared__ float tl[64 * 132];
    const int tid = threadIdx.x;
    #pragma unroll
    for (int rep = 0; rep < 8; ++rep) {
        const int idx = tid + 256 * rep;        // 0..2047 float4s
        const int b = idx >> 5, q = idx & 31;
        float4 uv = *(const float4*)(u + (size_t)b * 16384 + blk * 128 + 4 * q);
        *(float4*)&tl[b * 132 + 4 * q] = uv;
    }
    __syncthreads();
    #pragma unroll
    for (int rep = 0; rep < 32; ++rep) {
        const int row = rep * 4 + (tid >> 6);
        const int b = tid & 63;
        ut[(size_t)(blk * 128 + row) * 64 + b] = tl[b * 132 + row];
    }
}

// ---- r_weighted via MFMA: per-o GEMM C[16d x 64b] = W[o]^T · (c ⊙ u) ----
template <int UNIFORM>
__global__ __launch_bounds__(256) void r_weighted_mfma_kernel(
        const float* __restrict__ W, const float* __restrict__ u,
        const float* __restrict__ cbuf, float* __restrict__ sp) {
    const int o = blockIdx.x;
    const int st = blockIdx.y;
    __shared__ __align__(16) unsigned short Ahi[16 * 72];
    __shared__ __align__(16) unsigned short Alo[16 * 72];
    __shared__ __align__(16) unsigned short Bhi[64 * 72];
    __shared__ __align__(16) unsigned short Blo[64 * 72];
    const int tid = threadIdx.x;
    const int lane = tid & 63;
    const int w = tid >> 6;
    const int l15 = lane & 15;
    const int hi = lane >> 4;
    const int sb = tid >> 2;
    const int si = tid & 3;
    f32x4 acc = {0.f, 0.f, 0.f, 0.f};
    const float* Wo = W + (size_t)o * 262144;
    const int i_base = st * 256;
    #pragma unroll 1
    for (int iter = 0; iter < 32; ++iter) {
        const int i0 = i_base + iter * 8;
        __syncthreads();
        {
            float4 wv = *(const float4*)(Wo + (size_t)i0 * 128 + 4 * tid);
            const int i_l = tid >> 5;
            const int d = (tid >> 1) & 15;
            const int k0 = (tid & 1) * 4;
            unsigned short* dh = Ahi + d * 72 + i_l * 8 + k0;
            unsigned short* dl = Alo + d * 72 + i_l * 8 + k0;
            float vv[4] = {wv.x, wv.y, wv.z, wv.w};
            unsigned int h01, h23, l01, l23;
            unsigned short h, l;
            h = f2bf(vv[0]); l = f2bf(vv[0] - bf2f(h)); h01 = h; l01 = l;
            h = f2bf(vv[1]); l = f2bf(vv[1] - bf2f(h)); h01 |= (unsigned)h << 16; l01 |= (unsigned)l << 16;
            h = f2bf(vv[2]); l = f2bf(vv[2] - bf2f(h)); h23 = h; l23 = l;
            h = f2bf(vv[3]); l = f2bf(vv[3] - bf2f(h)); h23 |= (unsigned)h << 16; l23 |= (unsigned)l << 16;
            *(unsigned int*)dh = h01; *(unsigned int*)(dh + 2) = h23;
            *(unsigned int*)dl = l01; *(unsigned int*)(dl + 2) = l23;
        }
        #pragma unroll
        for (int half = 0; half < 2; ++half) {
            const int i_l = si + 4 * half;
            const float* up = u + (size_t)sb * 16384 + (size_t)(i0 + i_l) * 8;
            float4 u0 = *(const float4*)up;
            float4 u1 = *(const float4*)(up + 4);
            float cv = UNIFORM ? 0.01f
                               : cbuf[(size_t)sb * (NO * NI) + o * NI + i0 + i_l];
            float q[8] = {u0.x * cv, u0.y * cv, u0.z * cv, u0.w * cv,
                          u1.x * cv, u1.y * cv, u1.z * cv, u1.w * cv};
            uint4 ph, pl;
            unsigned short h0, h1, l0, l1;
            h0 = f2bf(q[0]); l0 = f2bf(q[0] - bf2f(h0));
            h1 = f2bf(q[1]); l1 = f2bf(q[1] - bf2f(h1));
            ph.x = h0 | ((unsigned)h1 << 16); pl.x = l0 | ((unsigned)l1 << 16);
            h0 = f2bf(q[2]); l0 = f2bf(q[2] - bf2f(h0));
            h1 = f2bf(q[3]); l1 = f2bf(q[3] - bf2f(h1));
            ph.y = h0 | ((unsigned)h1 << 16); pl.y = l0 | ((unsigned)l1 << 16);
            h0 = f2bf(q[4]); l0 = f2bf(q[4] - bf2f(h0));
            h1 = f2bf(q[5]); l1 = f2bf(q[5] - bf2f(h1));
            ph.z = h0 | ((unsigned)h1 << 16); pl.z = l0 | ((unsigned)l1 << 16);
            h0 = f2bf(q[6]); l0 = f2bf(q[6] - bf2f(h0));
            h1 = f2bf(q[7]); l1 = f2bf(q[7] - bf2f(h1));
            ph.w = h0 | ((unsigned)h1 << 16); pl.w = l0 | ((unsigned)l1 << 16);
            *(uint4*)(Bhi + sb * 72 + i_l * 8) = ph;
            *(uint4*)(Blo + sb * 72 + i_l * 8) = pl;
        }
        __syncthreads();
        #pragma unroll
        for (int ch = 0; ch < 2; ++ch) {
            bf16x8 ah = *(const bf16x8*)(Ahi + l15 * 72 + ch * 32 + hi * 8);
            bf16x8 al = *(const bf16x8*)(Alo + l15 * 72 + ch * 32 + hi * 8);
            bf16x8 bh = *(const bf16x8*)(Bhi + (w * 16 + l15) * 72 + ch * 32 + hi * 8);
            bf16x8 bl = *(const bf16x8*)(Blo + (w * 16 + l15) * 72 + ch * 32 + hi * 8);
            acc = __builtin_amdgcn_mfma_f32_16x16x32_bf16(ah, bh, acc, 0, 0, 0);
            acc = __builtin_amdgcn_mfma_f32_16x16x32_bf16(ah, bl, acc, 0, 0, 0);
            acc = __builtin_amdgcn_mfma_f32_16x16x32_bf16(al, bh, acc, 0, 0, 0);
        }
    }
    const int bg = w * 16 + l15;
    float4 st4;
    st4.x = acc[0]; st4.y = acc[1]; st4.z = acc[2]; st4.w = acc[3];
    *(float4*)&sp[(((size_t)o * 8 + st) * 64 + bg) * 16 + hi * 4] = st4;
}

// -------- reduce partials over st (8), squash over d, write v/out --------
__global__ __launch_bounds__(256) void squash_v_kernel(const float* __restrict__ sp,
        float* __restrict__ dest) {
    const int t = blockIdx.x * 256 + threadIdx.x;
    const int d = t & 15;
    const int cap = t >> 4;
    const int o = cap >> 6;
    const int bb = cap & 63;
    float s = 0.f;
    #pragma unroll
    for (int st = 0; st < 8; ++st)
        s += sp[(((size_t)o * 8 + st) * 64 + bb) * 16 + d];
    float s2 = s * s;
    #pragma unroll
    for (int off = 1; off < 16; off <<= 1)
        s2 += __shfl_xor(s2, off, 16);
    float scale = (s2 / (1.f + s2)) / sqrtf(s2 + 1e-8f);
    dest[(bb * NO + o) * ND + d] = s * scale;
}

// ---- r_logits via MFMA: per-o GEMM G[(i,k) x b] = [Wh|Wl] · [v...]; then
// in-register k-reduce with ut. A rows=(i,k), K=d padded 16->32 via split.
// MFMA1: Aext x [vh|vh] = Wh·vh + Wl·vh;  MFMA2: Aext x [vl|0] = Wh·vl.
template <int ADD>
__global__ __launch_bounds__(256) void r_logits_mfma_kernel(
        const float* __restrict__ W, const float* __restrict__ ut,
        const float* __restrict__ v, float* __restrict__ bbuf) {
    const int o = blockIdx.x;
    const int st = blockIdx.y;               // 128 i per block
    __shared__ __align__(16) unsigned short Aext[128 * 40];
    __shared__ __align__(16) unsigned short B1[64 * 40];
    __shared__ __align__(16) unsigned short B2[64 * 40];
    __shared__ float ul[128 * 66];
    const int tid = threadIdx.x;
    const int lane = tid & 63;
    const int w = tid >> 6;
    const int l15 = lane & 15;
    const int hi = lane >> 4;
    const float* Wo = W + (size_t)o * 262144;
    // stage B1/B2 once: B1[b][d'<16?vh:vh], B2[b][d'<16?vl:0]
    {
        const int b = tid >> 2;
        const int dq = (tid & 3) * 4;
        float4 vv = *(const float4*)&v[((size_t)b * NO + o) * ND + dq];
        float q[4] = {vv.x, vv.y, vv.z, vv.w};
        #pragma unroll
        for (int c = 0; c < 4; ++c) {
            unsigned short h = f2bf(q[c]);
            unsigned short l = f2bf(q[c] - bf2f(h));
            B1[b * 40 + dq + c] = h;
            B1[b * 40 + 16 + dq + c] = h;
            B2[b * 40 + dq + c] = l;
            B2[b * 40 + 16 + dq + c] = 0;
        }
    }
    __syncthreads();
    #pragma unroll 1
    for (int iter = 0; iter < 8; ++iter) {
        __syncthreads();
        // A stage: W[o, st*128+iter*16 .., 16 i x 128 dk] -> Aext[(i_l*8+k)][d | 16+d]
        #pragma unroll
        for (int rep = 0; rep < 2; ++rep) {
            const int off = 4 * tid + 1024 * rep;
            float4 wv = *(const float4*)(Wo + (size_t)(st * 128 + iter * 16) * 128 + off);
            const int i_l = off >> 7;
            const int d = (off >> 3) & 15;
            const int k0 = off & 7;
            float va[4] = {wv.x, wv.y, wv.z, wv.w};
            #pragma unroll
            for (int c = 0; c < 4; ++c) {
                unsigned short h = f2bf(va[c]);
                unsigned short l = f2bf(va[c] - bf2f(h));
                const int row = i_l * 8 + k0 + c;
                Aext[row * 40 + d] = h;
                Aext[row * 40 + 16 + d] = l;
            }
        }
        // u stage: ut rows for this iter's 16 i -> ul[row][b], pad 66
        const int base_row = (st * 128 + iter * 16) * 8;
        #pragma unroll
        for (int rep = 0; rep < 8; ++rep) {
            const int idx = tid + 256 * rep;
            const int row = idx >> 4, bq = idx & 15;
            float4 uv = *(const float4*)(ut + (size_t)(base_row + row) * 64 + 4 * bq);
            *(float4*)&ul[row * 66 + 4 * bq] = uv;
        }
        __syncthreads();
        // MFMA: 8 m-tiles x 2 (split) per wave; wave w owns b-tile w*16..+16
        f32x4 acc[8];
        bf16x8 bf1 = *(const bf16x8*)&B1[(w * 16 + l15) * 40 + hi * 8];
        bf16x8 bf2 = *(const bf16x8*)&B2[(w * 16 + l15) * 40 + hi * 8];
        #pragma unroll
        for (int mt = 0; mt < 8; ++mt) {
            f32x4 z = {0.f, 0.f, 0.f, 0.f};
            bf16x8 af = *(const bf16x8*)&Aext[(mt * 16 + l15) * 40 + hi * 8];
            z = __builtin_amdgcn_mfma_f32_16x16x32_bf16(af, bf1, z, 0, 0, 0);
            z = __builtin_amdgcn_mfma_f32_16x16x32_bf16(af, bf2, z, 0, 0, 0);
            acc[mt] = z;
        }
        // k-reduce: lane holds G rows mt*16 + hi*4 + r, col b = w*16+l15
        #pragma unroll
        for (int mt = 0; mt < 8; ++mt) {
            float partial = 0.f;
            #pragma unroll
            for (int r = 0; r < 4; ++r) {
                const int grow = mt * 16 + hi * 4 + r;
                partial = fmaf(acc[mt][r], ul[grow * 66 + w * 16 + l15], partial);
            }
            float sum = partial + __shfl_xor(partial, 16);
            if ((hi & 1) == 0) {
                const int i_glob = st * 128 + iter * 16 + mt * 2 + (hi >> 1);
                const int bg = w * 16 + l15;
                const size_t addr = (size_t)bg * (NO * NI) + (size_t)o * NI + i_glob;
                bbuf[addr] = (ADD ? bbuf[addr] : 0.f) + sum;
            }
        }
    }
}

// -------- softmax over o (axis=1) of b -> c --------
__global__ __launch_bounds__(256) void softmax_kernel(const float* __restrict__ bbuf,
        float* __restrict__ cbuf) {
    const int bb = blockIdx.x >> 3;
    const int i = (blockIdx.x & 7) * 256 + threadIdx.x;
    const float* col = bbuf + bb * (NO * NI) + i;
    float m = -1e30f;
    for (int o = 0; o < NO; ++o) m = fmaxf(m, col[o * NI]);
    float s = 0.f;
    for (int o = 0; o < NO; ++o) s += __expf(col[o * NI] - m);
    const float inv = 1.f / s;
    float* outp = cbuf + bb * (NO * NI) + i;
    for (int o = 0; o < NO; ++o) outp[o * NI] = __expf(col[o * NI] - m) * inv;
}

extern "C" void kernel_launch(void* const* d_in, const int* in_sizes, int n_in,
                              void* d_out, int out_size, void* d_ws, size_t ws_size,
                              hipStream_t stream) {
    (void)in_sizes; (void)n_in; (void)out_size; (void)ws_size;
    const float* x      = (const float*)d_in[0];
    const float* conv_w = (const float*)d_in[1];
    const float* conv_b = (const float*)d_in[2];
    const float* pcap_w = (const float*)d_in[3];
    const float* pcap_b = (const float*)d_in[4];
    const float* W      = (const float*)d_in[5];
    float* out = (float*)d_out;
    float* ws  = (float*)d_ws;
    unsigned short* h_hi = (unsigned short*)(ws + WS_H);
    unsigned short* h_lo = h_hi + 9437184;
    unsigned short* wBhi = (unsigned short*)(ws + WS_CB);
    unsigned short* wBlo = wBhi + 9437184;
    float* ut  = ws + WS_H;    // overlaps h (dead after conv2)
    float* u   = ws + WS_U;
    float* bbf = ws + WS_BB;
    float* cbf = ws + WS_CB;
    float* sp  = ws + WS_SP;
    float* v   = ws + WS_V;
    float* pp  = ws + WS_PP;

    wb_precompute_kernel<<<dim3(256, 4), 256, 0, stream>>>(pcap_w, wBhi, wBlo);
    conv1_kernel<<<dim3(64, 16), 256, 0, stream>>>(x, conv_w, conv_b, h_hi, h_lo);
    conv2_mfma_kernel<<<dim3(32, 2, 8), 256, 0, stream>>>(h_hi, h_lo, wBhi, wBlo, pp);
    reduce_bias_squash_kernel<<<512, 256, 0, stream>>>(pp, pcap_b, u);
    transpose_u_kernel<<<128, 256, 0, stream>>>(u, ut);
    // routing iter 0 (c uniform = 1/100)
    r_weighted_mfma_kernel<1><<<dim3(100, 8), 256, 0, stream>>>(W, u, nullptr, sp);
    squash_v_kernel<<<400, 256, 0, stream>>>(sp, v);
    r_logits_mfma_kernel<0><<<dim3(100, 16), 256, 0, stream>>>(W, ut, v, bbf);
    // routing iter 1
    softmax_kernel<<<512, 256, 0, stream>>>(bbf, cbf);
    r_weighted_mfma_kernel<0><<<dim3(100, 8), 256, 0, stream>>>(W, u, cbf, sp);
    squash_v_kernel<<<400, 256, 0, stream>>>(sp, v);
    r_logits_mfma_kernel<1><<<dim3(100, 16), 256, 0, stream>>>(W, ut, v, bbf);
    // routing iter 2
    softmax_kernel<<<512, 256, 0, stream>>>(bbf, cbf);
    r_weighted_mfma_kernel<0><<<dim3(100, 8), 256, 0, stream>>>(W, u, cbf, sp);
    squash_v_kernel<<<400, 256, 0, stream>>>(sp, out);
}